// Round 1
// baseline (4300.057 us; speedup 1.0000x reference)
//
#include <hip/hip_runtime.h>
#include <stdint.h>

#define T_   512
#define H_   256
#define OUTD 128

typedef unsigned long long u64;
typedef __attribute__((ext_vector_type(8))) short s8v;
typedef __attribute__((ext_vector_type(4))) float f4v;

__device__ __forceinline__ f4v mfma16x16x32(s8v a, s8v b, f4v c) {
  return __builtin_amdgcn_mfma_f32_16x16x32_bf16(a, b, c, 0, 0, 0);
}

// fp32 -> bf16 hi (truncate) + bf16 lo (RN of remainder)
__device__ __forceinline__ void split_bf16(float f, short &hi, short &lo) {
  unsigned u  = __float_as_uint(f);
  unsigned uh = u & 0xffff0000u;
  hi = (short)(uh >> 16);
  float r = f - __uint_as_float(uh);
  unsigned ur = __float_as_uint(r);
  lo = (short)((ur + 0x7fffu + ((ur >> 16) & 1u)) >> 16);
}

__device__ __forceinline__ unsigned pack_hilo(float f) {
  short hi, lo; split_bf16(f, hi, lo);
  return ((unsigned)(unsigned short)hi << 16) | (unsigned)(unsigned short)lo;
}

__device__ __forceinline__ float sig_(float x) { return 1.f / (1.f + __expf(-x)); }
__device__ __forceinline__ float th_(float x)  { float e = __expf(2.f * x); return 1.f - 2.f / (e + 1.f); }

struct SMem {
  short xhi[16][264], xlo[16][264];
  short hhi[16][264], hlo[16][264];
  float gl[4][16][17];
  float bias[64];
};  // 38400 B

// Exchange protocol: entry = u64 (tag<<32 | bf16hi<<16 | bf16lo), tag = step+1.
// Double-buffered by step parity. Tag-equality spin on exactly the data each
// thread consumes (8B atomicity => tag/data consistent; no fences, no RMW).
// NEW: selective spin — per-entry pending mask; only not-yet-valid entries are
// re-loaded each poll, and each entry is committed to LDS the moment its tag
// matches. Layer1 polls its x (layer0 h) and own h in ONE merged loop so both
// round-trips overlap. Cross-layer back-pressure: layer1 publishes rflag=s+1
// after loading layer0 step-s data; layer0's check is now issued BEFORE the
// MFMA phase (ordering to the publish store is provided by the gl barrier).
template <int LAYER>
__device__ __forceinline__ void lstm_body(
    SMem* sm,
    const float* __restrict__ xin,
    const float* __restrict__ Wih, const float* __restrict__ Whh,
    const float* __restrict__ bih, const float* __restrict__ bhh,
    u64* bx_x,        // LAYER==1: consumed exchange (layer0 h)
    u64* bx_own,      // produced exchange (own h recurrence; layer0: also layer1's x)
    unsigned* rflag,  // [16 groups][16 members], stride 16 dwords
    float* h1l,       // LAYER==1: last h out [256,256]
    int g, int mem)
{
  constexpr int KX  = (LAYER == 0) ? 128 : 256;
  constexpr int NKX = KX / 32;
  const int tid = threadIdx.x;
  const int w = tid >> 6, lane = tid & 63, n = lane & 15, q = lane >> 4;
  const int bb = tid >> 4, uu = tid & 15;
  const int B0 = g * 16, U0 = mem * 16;

  // ---- weight slice -> register B-fragments (bf16 hi/lo), once ----
  s8v wxh[NKX], wxl[NKX], whhh[8], whhl[8];
  {
    const int row = w * 256 + U0 + n;
    #pragma unroll
    for (int kf = 0; kf < NKX; ++kf) {
      s8v vh, vl;
      #pragma unroll
      for (int j = 0; j < 8; ++j) { short hi, lo; split_bf16(Wih[row * KX + kf * 32 + q * 8 + j], hi, lo); vh[j] = hi; vl[j] = lo; }
      wxh[kf] = vh; wxl[kf] = vl;
    }
    #pragma unroll
    for (int kf = 0; kf < 8; ++kf) {
      s8v vh, vl;
      #pragma unroll
      for (int j = 0; j < 8; ++j) { short hi, lo; split_bf16(Whh[row * 256 + kf * 32 + q * 8 + j], hi, lo); vh[j] = hi; vl[j] = lo; }
      whhh[kf] = vh; whhl[kf] = vl;
    }
  }
  if (tid < 64) {
    int gate = tid >> 4, u = tid & 15;
    int grow = gate * 256 + U0 + u;
    sm->bias[tid] = bih[grow] + bhh[grow];
  }

  u64* own = bx_own + (size_t)g * 2 * 4096;
  u64* src = (LAYER == 1) ? (bx_x + (size_t)g * 2 * 4096) : nullptr;
  unsigned* rfg    = rflag + g * 256;       // member m's flag at rfg[m*16]
  unsigned* rfself = rfg + mem * 16;

  float c = 0.f;

  for (int s = 0; s < T_; ++s) {
    // ---- layer0: fp32 x prefetch (issued early, overlaps spins) ----
    float xv[8];
    if (LAYER == 0) {
      const float* px = xin + ((size_t)(B0 + bb) * T_ + s) * 128 + uu * 8;
      float4 v0 = *(const float4*)px, v1 = *(const float4*)(px + 4);
      xv[0] = v0.x; xv[1] = v0.y; xv[2] = v0.z; xv[3] = v0.w;
      xv[4] = v1.x; xv[5] = v1.y; xv[6] = v1.z; xv[7] = v1.w;
    }

    // ---- s==0: zero h staging (no producer yet) ----
    if (s == 0) {
      #pragma unroll
      for (int i = 0; i < 16; ++i) { sm->hhi[i][tid] = 0; sm->hlo[i][tid] = 0; }
    }

    // ---- merged selective spin: layer1's x (layer0 h, step s) + own h_{s-1} ----
    {
      unsigned pendx = (LAYER == 1) ? 0xffffu : 0u;
      unsigned pendh = (s > 0) ? 0xffffu : 0u;
      const u64* pbx = (LAYER == 1) ? (src + (size_t)(s & 1) * 4096) : nullptr;
      const u64* pbh = own + (size_t)((s - 1) & 1) * 4096;  // s==0: unused (pendh=0)
      const unsigned xtag = (unsigned)(s + 1), htag = (unsigned)s;
      int it = 0;
      while (pendx | pendh) {
        u64 tx[16], th[16];
        // issue all pending loads first (keeps first-pass MLP: up to 32 in flight)
        if (LAYER == 1) {
          #pragma unroll
          for (int i = 0; i < 16; ++i)
            if ((pendx >> i) & 1)
              tx[i] = __hip_atomic_load(&pbx[i * 256 + tid], __ATOMIC_RELAXED, __HIP_MEMORY_SCOPE_AGENT);
        }
        #pragma unroll
        for (int i = 0; i < 16; ++i)
          if ((pendh >> i) & 1)
            th[i] = __hip_atomic_load(&pbh[i * 256 + tid], __ATOMIC_RELAXED, __HIP_MEMORY_SCOPE_AGENT);
        // check + commit valid entries straight to LDS (frees registers, spreads writes)
        if (LAYER == 1) {
          #pragma unroll
          for (int i = 0; i < 16; ++i)
            if (((pendx >> i) & 1) && (unsigned)(tx[i] >> 32) == xtag) {
              unsigned d = (unsigned)tx[i];
              sm->xhi[i][tid] = (short)(d >> 16);
              sm->xlo[i][tid] = (short)(d & 0xffffu);
              pendx &= ~(1u << i);
            }
        }
        #pragma unroll
        for (int i = 0; i < 16; ++i)
          if (((pendh >> i) & 1) && (unsigned)(th[i] >> 32) == htag) {
            unsigned d = (unsigned)th[i];
            sm->hhi[i][tid] = (short)(d >> 16);
            sm->hlo[i][tid] = (short)(d & 0xffffu);
            pendh &= ~(1u << i);
          }
        if (pendx | pendh) {
          if (++it >= 50000) break;          // no-hang safety
          __builtin_amdgcn_s_sleep(1);
        }
      }
    }

    // ---- layer0: stage fp32 x as bf16 hi/lo ----
    if (LAYER == 0) {
      s8v vh, vl;
      #pragma unroll
      for (int j = 0; j < 8; ++j) { short hi, lo; split_bf16(xv[j], hi, lo); vh[j] = hi; vl[j] = lo; }
      *(s8v*)&sm->xhi[bb][uu * 8] = vh;
      *(s8v*)&sm->xlo[bb][uu * 8] = vl;
    }
    __syncthreads();

    // layer1: publish read-progress (all threads' loads completed at barrier)
    if (LAYER == 1 && tid == 0)
      __hip_atomic_store(rfself, (unsigned)(s + 1), __ATOMIC_RELAXED, __HIP_MEMORY_SCOPE_AGENT);

    // ---- layer0: back-pressure check, issued EARLY so the round-trip hides
    //      under MFMA + activations; publish is ordered after it by the gl
    //      barrier below. Condition: layer1 consumed step s-2 (rflag >= s-1)
    //      before we overwrite slot (s&1). ----
    if (LAYER == 0 && s >= 2 && w == 0) {
      const unsigned tgt = (unsigned)(s - 1); int it2 = 0;
      for (;;) {
        unsigned v = (lane < 16)
          ? __hip_atomic_load(&rfg[lane * 16], __ATOMIC_RELAXED, __HIP_MEMORY_SCOPE_AGENT)
          : tgt;
        if (__all((int)(v >= tgt))) break;
        if (++it2 >= 50000) break;
        __builtin_amdgcn_s_sleep(1);
      }
    }

    // ---- bf16x3 MFMA: hi*hi + lo*hi + hi*lo chains ----
    f4v a0 = {0.f, 0.f, 0.f, 0.f}, a1 = a0, a2 = a0;
    #pragma unroll
    for (int kf = 0; kf < NKX; ++kf) {
      s8v ah = *(const s8v*)&sm->xhi[n][kf * 32 + q * 8];
      s8v al = *(const s8v*)&sm->xlo[n][kf * 32 + q * 8];
      a0 = mfma16x16x32(ah, wxh[kf], a0);
      a1 = mfma16x16x32(al, wxh[kf], a1);
      a2 = mfma16x16x32(ah, wxl[kf], a2);
    }
    #pragma unroll
    for (int kf = 0; kf < 8; ++kf) {
      s8v ah = *(const s8v*)&sm->hhi[n][kf * 32 + q * 8];
      s8v al = *(const s8v*)&sm->hlo[n][kf * 32 + q * 8];
      a0 = mfma16x16x32(ah, whhh[kf], a0);
      a1 = mfma16x16x32(al, whhh[kf], a1);
      a2 = mfma16x16x32(ah, whhl[kf], a2);
    }
    f4v D = a0 + (a1 + a2);
    #pragma unroll
    for (int r = 0; r < 4; ++r) sm->gl[w][q * 4 + r][n] = D[r];
    __syncthreads();

    // ---- activations + state ----
    float pi = sm->gl[0][bb][uu] + sm->bias[uu];
    float pf = sm->gl[1][bb][uu] + sm->bias[16 + uu];
    float pg = sm->gl[2][bb][uu] + sm->bias[32 + uu];
    float po = sm->gl[3][bb][uu] + sm->bias[48 + uu];
    float ig = sig_(pi), fg = sig_(pf), gg = th_(pg), og = sig_(po);
    c = fg * c + ig * gg;
    float h = og * th_(c);

    // ---- publish h (tagged, fire-and-forget; rflag check already done) ----
    u64 val = ((u64)(unsigned)(s + 1) << 32) | (u64)pack_hilo(h);
    __hip_atomic_store(&own[(size_t)(s & 1) * 4096 + bb * 256 + U0 + uu], val,
                       __ATOMIC_RELAXED, __HIP_MEMORY_SCOPE_AGENT);

    if (LAYER == 1 && s == T_ - 1)
      h1l[(B0 + bb) * H_ + U0 + uu] = h;
  }
}

__global__ __launch_bounds__(256, 2) void lstm_fused(
    const float* __restrict__ x,
    const float* __restrict__ Wih0, const float* __restrict__ Whh0,
    const float* __restrict__ bih0, const float* __restrict__ bhh0,
    const float* __restrict__ Wih1, const float* __restrict__ Whh1,
    const float* __restrict__ bih1, const float* __restrict__ bhh1,
    u64* bx0, u64* bx1, unsigned* rflag, float* h1l)
{
  __shared__ SMem sm;
  const int bid = blockIdx.x;
  if (bid < 256) {
    lstm_body<0>(&sm, x, Wih0, Whh0, bih0, bhh0, nullptr, bx0, rflag, nullptr,
                 bid >> 4, bid & 15);
  } else {
    const int b = bid - 256;
    lstm_body<1>(&sm, nullptr, Wih1, Whh1, bih1, bhh1, bx0, bx1, rflag, h1l,
                 b >> 4, b & 15);
  }
}

__global__ void fc_kernel(const float* __restrict__ h1l, const float* __restrict__ Wfc,
                          float* __restrict__ out) {
  __shared__ float hs[H_];
  const int b = blockIdx.x, o = threadIdx.x;
  hs[o]       = h1l[b * H_ + o];
  hs[o + 128] = h1l[b * H_ + o + 128];
  __syncthreads();
  float acc = 0.f;
  #pragma unroll 8
  for (int u = 0; u < H_; u += 4) {
    float4 wv = *(const float4*)&Wfc[o * H_ + u];
    acc += wv.x * hs[u] + wv.y * hs[u + 1] + wv.z * hs[u + 2] + wv.w * hs[u + 3];
  }
  out[b * OUTD + o] = acc;
}

extern "C" void kernel_launch(void* const* d_in, const int* in_sizes, int n_in,
                              void* d_out, int out_size, void* d_ws, size_t ws_size,
                              hipStream_t stream) {
  const float* x    = (const float*)d_in[0];
  const float* Wih0 = (const float*)d_in[1];
  const float* Whh0 = (const float*)d_in[2];
  const float* bih0 = (const float*)d_in[3];
  const float* bhh0 = (const float*)d_in[4];
  const float* Wih1 = (const float*)d_in[5];
  const float* Whh1 = (const float*)d_in[6];
  const float* bih1 = (const float*)d_in[7];
  const float* bhh1 = (const float*)d_in[8];
  const float* Wfc  = (const float*)d_in[9];

  // ws layout: bx0 (1 MiB) | bx1 (1 MiB) | rflag (16 KiB) | h1l (256 KiB)
  u64*      bx0   = (u64*)d_ws;            // 16*2*4096
  u64*      bx1   = bx0 + 131072;          // 16*2*4096
  unsigned* rflag = (unsigned*)(bx1 + 131072);  // 16*16*16
  float*    h1l   = (float*)(rflag + 4096);     // 256*256

  // rflag must start at 0 (poison 0xAA.. would spoof the >= back-pressure check;
  // exchange tags use equality so poison can never match them).
  hipMemsetAsync(rflag, 0, 4096 * sizeof(unsigned), stream);

  lstm_fused<<<512, 256, 0, stream>>>(x, Wih0, Whh0, bih0, bhh0,
                                      Wih1, Whh1, bih1, bhh1,
                                      bx0, bx1, rflag, h1l);
  fc_kernel<<<256, 128, 0, stream>>>(h1l, Wfc, (float*)d_out);
}

// Round 2
// 3381.059 us; speedup vs baseline: 1.2718x; 1.2718x over previous
//
#include <hip/hip_runtime.h>
#include <stdint.h>

#define T_   512
#define H_   256
#define OUTD 128

typedef unsigned long long u64;
typedef __attribute__((ext_vector_type(8))) short s8v;
typedef __attribute__((ext_vector_type(4))) float f4v;

__device__ __forceinline__ f4v mfma16x16x32(s8v a, s8v b, f4v c) {
  return __builtin_amdgcn_mfma_f32_16x16x32_bf16(a, b, c, 0, 0, 0);
}

// fp32 -> bf16 hi (truncate) + bf16 lo (RN of remainder)
__device__ __forceinline__ void split_bf16(float f, short &hi, short &lo) {
  unsigned u  = __float_as_uint(f);
  unsigned uh = u & 0xffff0000u;
  hi = (short)(uh >> 16);
  float r = f - __uint_as_float(uh);
  unsigned ur = __float_as_uint(r);
  lo = (short)((ur + 0x7fffu + ((ur >> 16) & 1u)) >> 16);
}

__device__ __forceinline__ unsigned pack_hilo(float f) {
  short hi, lo; split_bf16(f, hi, lo);
  return ((unsigned)(unsigned short)hi << 16) | (unsigned)(unsigned short)lo;
}

__device__ __forceinline__ float sig_(float x) { return 1.f / (1.f + __expf(-x)); }
__device__ __forceinline__ float th_(float x)  { float e = __expf(2.f * x); return 1.f - 2.f / (e + 1.f); }

struct SMem {
  short xhi[16][264], xlo[16][264];
  short hhi[16][264], hlo[16][264];
  float gl[4][16][17];
  float bias[64];
};  // 38400 B

// Exchange protocol (tags = ground truth, flags = advisory gate):
//   entry = u64 (tag<<32 | bf16hi<<16 | bf16lo), tag = step+1, double-buffered
//   by step parity; tag-equality spin on exactly the data each thread consumes
//   (8B atomicity => tag/data consistent; no fences needed for correctness).
// NEW: per-producer monotone step flag (flag0/flag1, one 64B line per group).
//   Producers store flag after a post-publish barrier (issue-ordered hint).
//   Consumers: wave-0 spins on the 16-32 flag dwords (other waves parked at a
//   barrier, not polling), THEN the tagged data pass runs — expected 1 iter.
//   This cuts poll re-read traffic ~10x; flags can never cause wrong data
//   (tags still verified), only a rare extra data-pass iteration.
// Layer0's rflag back-pressure poll is folded into the same gate (lanes 16-31).
template <int LAYER>
__device__ __forceinline__ void lstm_body(
    SMem* sm,
    const float* __restrict__ xin,
    const float* __restrict__ Wih, const float* __restrict__ Whh,
    const float* __restrict__ bih, const float* __restrict__ bhh,
    u64* bx_x,        // LAYER==1: consumed exchange (layer0 h)
    u64* bx_own,      // produced exchange (own h recurrence; layer0: also layer1's x)
    unsigned* rflag,  // [16 groups][16 members], stride 16 dwords
    unsigned* pf_src, // LAYER==1: flags of consumed exchange (flag0)
    unsigned* pf_own, // flags of own exchange (L0: flag0, L1: flag1)
    float* h1l,       // LAYER==1: last h out [256,256]
    int g, int mem)
{
  constexpr int KX  = (LAYER == 0) ? 128 : 256;
  constexpr int NKX = KX / 32;
  const int tid = threadIdx.x;
  const int w = tid >> 6, lane = tid & 63, n = lane & 15, q = lane >> 4;
  const int bb = tid >> 4, uu = tid & 15;
  const int B0 = g * 16, U0 = mem * 16;

  // ---- weight slice -> register B-fragments (bf16 hi/lo), once ----
  s8v wxh[NKX], wxl[NKX], whhh[8], whhl[8];
  {
    const int row = w * 256 + U0 + n;
    #pragma unroll
    for (int kf = 0; kf < NKX; ++kf) {
      s8v vh, vl;
      #pragma unroll
      for (int j = 0; j < 8; ++j) { short hi, lo; split_bf16(Wih[row * KX + kf * 32 + q * 8 + j], hi, lo); vh[j] = hi; vl[j] = lo; }
      wxh[kf] = vh; wxl[kf] = vl;
    }
    #pragma unroll
    for (int kf = 0; kf < 8; ++kf) {
      s8v vh, vl;
      #pragma unroll
      for (int j = 0; j < 8; ++j) { short hi, lo; split_bf16(Whh[row * 256 + kf * 32 + q * 8 + j], hi, lo); vh[j] = hi; vl[j] = lo; }
      whhh[kf] = vh; whhl[kf] = vl;
    }
  }
  if (tid < 64) {
    int gate = tid >> 4, u = tid & 15;
    int grow = gate * 256 + U0 + u;
    sm->bias[tid] = bih[grow] + bhh[grow];
  }

  u64* own = bx_own + (size_t)g * 2 * 4096;
  u64* src = (LAYER == 1) ? (bx_x + (size_t)g * 2 * 4096) : nullptr;
  unsigned* rfg    = rflag + g * 256;       // member m's flag at rfg[m*16]
  unsigned* rfself = rfg + mem * 16;
  unsigned* pfs = (LAYER == 1) ? (pf_src + g * 16) : nullptr;
  unsigned* pfo = pf_own + g * 16;

  float c = 0.f;

  for (int s = 0; s < T_; ++s) {
    // ---- layer0: fp32 x prefetch (issued early, overlaps gate) ----
    float xv[8];
    if (LAYER == 0) {
      const float* px = xin + ((size_t)(B0 + bb) * T_ + s) * 128 + uu * 8;
      float4 v0 = *(const float4*)px, v1 = *(const float4*)(px + 4);
      xv[0] = v0.x; xv[1] = v0.y; xv[2] = v0.z; xv[3] = v0.w;
      xv[4] = v1.x; xv[5] = v1.y; xv[6] = v1.z; xv[7] = v1.w;
    }

    // ---- cheap flag gate: wave 0 polls 64B of flags; others park at barrier.
    //      lanes 0-15:  own-h flags >= s        (h(s-1) published with flag s)
    //      lanes 16-31: L1: x flags >= s+1;  L0: rflag >= s-1 (back-pressure,
    //                   folded here; the publish below is ordered after the
    //                   gate barrier, so the old pre-publish spin is removed)
    if (w == 0) {
      int it = 0;
      for (;;) {
        bool ok = true;
        if (lane < 16) {
          if (s > 0)
            ok = __hip_atomic_load(&pfo[lane], __ATOMIC_RELAXED, __HIP_MEMORY_SCOPE_AGENT) >= (unsigned)s;
        } else if (lane < 32) {
          if (LAYER == 1)
            ok = __hip_atomic_load(&pfs[lane - 16], __ATOMIC_RELAXED, __HIP_MEMORY_SCOPE_AGENT) >= (unsigned)(s + 1);
          else if (s >= 2)
            ok = __hip_atomic_load(&rfg[(lane - 16) * 16], __ATOMIC_RELAXED, __HIP_MEMORY_SCOPE_AGENT) >= (unsigned)(s - 1);
        }
        if (__all((int)ok)) break;
        if (++it >= 200000) break;          // advisory only; tags still verified
        __builtin_amdgcn_s_sleep(1);
      }
    }
    __syncthreads();

    // ---- layer1: tagged data pass for layer0's step-s h (= our x) ----
    if (LAYER == 1) {
      const u64* pbx = src + (size_t)(s & 1) * 4096;
      const unsigned xtag = (unsigned)(s + 1);
      u64 xv64[16]; int it = 0;
      for (;;) {
        bool ok = true;
        #pragma unroll
        for (int i = 0; i < 16; ++i)
          xv64[i] = __hip_atomic_load(&pbx[i * 256 + tid], __ATOMIC_RELAXED, __HIP_MEMORY_SCOPE_AGENT);
        #pragma unroll
        for (int i = 0; i < 16; ++i) ok &= ((unsigned)(xv64[i] >> 32) == xtag);
        if (ok) break;
        if (++it >= 50000) break;          // no-hang safety
        __builtin_amdgcn_s_sleep(1);
      }
      #pragma unroll
      for (int i = 0; i < 16; ++i) {
        unsigned d = (unsigned)xv64[i];
        sm->xhi[i][tid] = (short)(d >> 16);
        sm->xlo[i][tid] = (short)(d & 0xffffu);
      }
    }

    // ---- tagged data pass for own group's h_{s-1} ----
    if (s > 0) {
      const u64* pbh = own + (size_t)((s - 1) & 1) * 4096;
      const unsigned htag = (unsigned)s;
      u64 hv64[16]; int it = 0;
      for (;;) {
        bool ok = true;
        #pragma unroll
        for (int i = 0; i < 16; ++i)
          hv64[i] = __hip_atomic_load(&pbh[i * 256 + tid], __ATOMIC_RELAXED, __HIP_MEMORY_SCOPE_AGENT);
        #pragma unroll
        for (int i = 0; i < 16; ++i) ok &= ((unsigned)(hv64[i] >> 32) == htag);
        if (ok) break;
        if (++it >= 50000) break;
        __builtin_amdgcn_s_sleep(1);
      }
      #pragma unroll
      for (int i = 0; i < 16; ++i) {
        unsigned d = (unsigned)hv64[i];
        sm->hhi[i][tid] = (short)(d >> 16);
        sm->hlo[i][tid] = (short)(d & 0xffffu);
      }
    } else {
      #pragma unroll
      for (int i = 0; i < 16; ++i) { sm->hhi[i][tid] = 0; sm->hlo[i][tid] = 0; }
    }

    // ---- layer0: stage fp32 x as bf16 hi/lo ----
    if (LAYER == 0) {
      s8v vh, vl;
      #pragma unroll
      for (int j = 0; j < 8; ++j) { short hi, lo; split_bf16(xv[j], hi, lo); vh[j] = hi; vl[j] = lo; }
      *(s8v*)&sm->xhi[bb][uu * 8] = vh;
      *(s8v*)&sm->xlo[bb][uu * 8] = vl;
    }
    __syncthreads();

    // layer1: publish read-progress (all threads' loads completed at barrier)
    if (LAYER == 1 && tid == 0)
      __hip_atomic_store(rfself, (unsigned)(s + 1), __ATOMIC_RELAXED, __HIP_MEMORY_SCOPE_AGENT);

    // ---- bf16x3 MFMA: hi*hi + lo*hi + hi*lo chains ----
    f4v a0 = {0.f, 0.f, 0.f, 0.f}, a1 = a0, a2 = a0;
    #pragma unroll
    for (int kf = 0; kf < NKX; ++kf) {
      s8v ah = *(const s8v*)&sm->xhi[n][kf * 32 + q * 8];
      s8v al = *(const s8v*)&sm->xlo[n][kf * 32 + q * 8];
      a0 = mfma16x16x32(ah, wxh[kf], a0);
      a1 = mfma16x16x32(al, wxh[kf], a1);
      a2 = mfma16x16x32(ah, wxl[kf], a2);
    }
    #pragma unroll
    for (int kf = 0; kf < 8; ++kf) {
      s8v ah = *(const s8v*)&sm->hhi[n][kf * 32 + q * 8];
      s8v al = *(const s8v*)&sm->hlo[n][kf * 32 + q * 8];
      a0 = mfma16x16x32(ah, whhh[kf], a0);
      a1 = mfma16x16x32(al, whhh[kf], a1);
      a2 = mfma16x16x32(ah, whhl[kf], a2);
    }
    f4v D = a0 + (a1 + a2);
    #pragma unroll
    for (int r = 0; r < 4; ++r) sm->gl[w][q * 4 + r][n] = D[r];
    __syncthreads();

    // ---- activations + state ----
    float pi = sm->gl[0][bb][uu] + sm->bias[uu];
    float pf = sm->gl[1][bb][uu] + sm->bias[16 + uu];
    float pg = sm->gl[2][bb][uu] + sm->bias[32 + uu];
    float po = sm->gl[3][bb][uu] + sm->bias[48 + uu];
    float ig = sig_(pi), fg = sig_(pf), gg = th_(pg), og = sig_(po);
    c = fg * c + ig * gg;
    float h = og * th_(c);

    // ---- publish h (tagged; back-pressure already enforced by the gate) ----
    u64 val = ((u64)(unsigned)(s + 1) << 32) | (u64)pack_hilo(h);
    __hip_atomic_store(&own[(size_t)(s & 1) * 4096 + bb * 256 + U0 + uu], val,
                       __ATOMIC_RELAXED, __HIP_MEMORY_SCOPE_AGENT);

    // ---- advisory flag: all publish stores issued before the flag issues ----
    __syncthreads();
    if (tid == 0)
      __hip_atomic_store(&pfo[mem], (unsigned)(s + 1), __ATOMIC_RELAXED, __HIP_MEMORY_SCOPE_AGENT);

    if (LAYER == 1 && s == T_ - 1)
      h1l[(B0 + bb) * H_ + U0 + uu] = h;
  }
}

__global__ __launch_bounds__(256, 2) void lstm_fused(
    const float* __restrict__ x,
    const float* __restrict__ Wih0, const float* __restrict__ Whh0,
    const float* __restrict__ bih0, const float* __restrict__ bhh0,
    const float* __restrict__ Wih1, const float* __restrict__ Whh1,
    const float* __restrict__ bih1, const float* __restrict__ bhh1,
    u64* bx0, u64* bx1, unsigned* rflag, unsigned* flag0, unsigned* flag1,
    float* h1l)
{
  __shared__ SMem sm;
  const int bid = blockIdx.x;
  if (bid < 256) {
    lstm_body<0>(&sm, x, Wih0, Whh0, bih0, bhh0, nullptr, bx0, rflag,
                 nullptr, flag0, nullptr, bid >> 4, bid & 15);
  } else {
    const int b = bid - 256;
    lstm_body<1>(&sm, nullptr, Wih1, Whh1, bih1, bhh1, bx0, bx1, rflag,
                 flag0, flag1, h1l, b >> 4, b & 15);
  }
}

__global__ void fc_kernel(const float* __restrict__ h1l, const float* __restrict__ Wfc,
                          float* __restrict__ out) {
  __shared__ float hs[H_];
  const int b = blockIdx.x, o = threadIdx.x;
  hs[o]       = h1l[b * H_ + o];
  hs[o + 128] = h1l[b * H_ + o + 128];
  __syncthreads();
  float acc = 0.f;
  #pragma unroll 8
  for (int u = 0; u < H_; u += 4) {
    float4 wv = *(const float4*)&Wfc[o * H_ + u];
    acc += wv.x * hs[u] + wv.y * hs[u + 1] + wv.z * hs[u + 2] + wv.w * hs[u + 3];
  }
  out[b * OUTD + o] = acc;
}

extern "C" void kernel_launch(void* const* d_in, const int* in_sizes, int n_in,
                              void* d_out, int out_size, void* d_ws, size_t ws_size,
                              hipStream_t stream) {
  const float* x    = (const float*)d_in[0];
  const float* Wih0 = (const float*)d_in[1];
  const float* Whh0 = (const float*)d_in[2];
  const float* bih0 = (const float*)d_in[3];
  const float* bhh0 = (const float*)d_in[4];
  const float* Wih1 = (const float*)d_in[5];
  const float* Whh1 = (const float*)d_in[6];
  const float* bih1 = (const float*)d_in[7];
  const float* bhh1 = (const float*)d_in[8];
  const float* Wfc  = (const float*)d_in[9];

  // ws layout: bx0 (1MiB) | bx1 (1MiB) | rflag (16KiB) | flag0 (1KiB) |
  //            flag1 (1KiB) | h1l (256KiB)
  u64*      bx0   = (u64*)d_ws;                  // 16*2*4096
  u64*      bx1   = bx0 + 131072;                // 16*2*4096
  unsigned* rflag = (unsigned*)(bx1 + 131072);   // 16*16*16
  unsigned* flag0 = rflag + 4096;                // 16*16
  unsigned* flag1 = flag0 + 256;                 // 16*16
  float*    h1l   = (float*)(flag1 + 256);       // 256*256

  // rflag + flags must start at 0 (monotone >= checks; poison would spoof the
  // gate — harmless for flags since tags are still verified, but rflag needs 0.
  // Exchange tags use equality so bx poison can never match them.)
  hipMemsetAsync(rflag, 0, (4096 + 512) * sizeof(unsigned), stream);

  lstm_fused<<<512, 256, 0, stream>>>(x, Wih0, Whh0, bih0, bhh0,
                                      Wih1, Whh1, bih1, bhh1,
                                      bx0, bx1, rflag, flag0, flag1, h1l);
  fc_kernel<<<256, 128, 0, stream>>>(h1l, Wfc, (float*)d_out);
}

// Round 3
// 2784.566 us; speedup vs baseline: 1.5442x; 1.2142x over previous
//
#include <hip/hip_runtime.h>
#include <stdint.h>

#define T_   512
#define H_   256
#define OUTD 128

typedef unsigned long long u64;
typedef __attribute__((ext_vector_type(8))) short s8v;
typedef __attribute__((ext_vector_type(4))) float f4v;

__device__ __forceinline__ f4v mfma16x16x32(s8v a, s8v b, f4v c) {
  return __builtin_amdgcn_mfma_f32_16x16x32_bf16(a, b, c, 0, 0, 0);
}

// fp32 -> bf16 hi (truncate) + bf16 lo (RN of remainder)
__device__ __forceinline__ void split_bf16(float f, short &hi, short &lo) {
  unsigned u  = __float_as_uint(f);
  unsigned uh = u & 0xffff0000u;
  hi = (short)(uh >> 16);
  float r = f - __uint_as_float(uh);
  unsigned ur = __float_as_uint(r);
  lo = (short)((ur + 0x7fffu + ((ur >> 16) & 1u)) >> 16);
}

__device__ __forceinline__ unsigned pack_hilo(float f) {
  short hi, lo; split_bf16(f, hi, lo);
  return ((unsigned)(unsigned short)hi << 16) | (unsigned)(unsigned short)lo;
}

__device__ __forceinline__ float sig_(float x) { return 1.f / (1.f + __expf(-x)); }
__device__ __forceinline__ float th_(float x)  { float e = __expf(2.f * x); return 1.f - 2.f / (e + 1.f); }

struct SMem {
  short xhi[16][264], xlo[16][264];
  short hhi[16][264], hlo[16][264];
  float gl[4][16][17];
  float bias[64];
};  // 38400 B

// Exchange protocol: entry = u64 (tag<<32 | bf16hi<<16 | bf16lo), tag = step+1.
// bx0 (layer0 h / layer1 x) is DEPTH-4 buffered (slot = s&3); bx1 (layer1 own
// recurrence) stays parity-2. Tag-equality spin on exactly the data each
// thread consumes (8B atomicity => tag/data consistent; no fences, no RMW).
// Own-group recurrence is self-synchronizing at depth>=2 (a member can only
// publish step s+1 after all members published step s, which required them to
// have consumed step s-1). Cross-layer back-pressure with depth 4: L0 at step
// s overwrites x(s-4), so it needs rflag >= s-3 — in steady state (lag 1-2)
// this holds at step START, so the rflag load is PREFETCHED at the step top
// and only evaluated before publish (RT hidden under the whole step).
// L1's x(s) is published by L0 >=1 full step earlier, so its 16 loads are
// issued BEFORE the own-h spin and verified after it (x RT hidden under h RT);
// rare-miss fallback is the original full spin.
template <int LAYER>
__device__ __forceinline__ void lstm_body(
    SMem* sm,
    const float* __restrict__ xin,
    const float* __restrict__ Wih, const float* __restrict__ Whh,
    const float* __restrict__ bih, const float* __restrict__ bhh,
    u64* bx_x,        // LAYER==1: consumed exchange (layer0 h, depth 4)
    u64* bx_own,      // produced exchange (L0: bx0 depth 4; L1: bx1 depth 2)
    unsigned* rflag,  // [16 groups][16 members], stride 16 dwords
    float* h1l,       // LAYER==1: last h out [256,256]
    int g, int mem)
{
  constexpr int KX  = (LAYER == 0) ? 128 : 256;
  constexpr int NKX = KX / 32;
  constexpr int OD  = (LAYER == 0) ? 4 : 2;   // own exchange depth
  const int tid = threadIdx.x;
  const int w = tid >> 6, lane = tid & 63, n = lane & 15, q = lane >> 4;
  const int bb = tid >> 4, uu = tid & 15;
  const int B0 = g * 16, U0 = mem * 16;

  // ---- weight slice -> register B-fragments (bf16 hi/lo), once ----
  s8v wxh[NKX], wxl[NKX], whhh[8], whhl[8];
  {
    const int row = w * 256 + U0 + n;
    #pragma unroll
    for (int kf = 0; kf < NKX; ++kf) {
      s8v vh, vl;
      #pragma unroll
      for (int j = 0; j < 8; ++j) { short hi, lo; split_bf16(Wih[row * KX + kf * 32 + q * 8 + j], hi, lo); vh[j] = hi; vl[j] = lo; }
      wxh[kf] = vh; wxl[kf] = vl;
    }
    #pragma unroll
    for (int kf = 0; kf < 8; ++kf) {
      s8v vh, vl;
      #pragma unroll
      for (int j = 0; j < 8; ++j) { short hi, lo; split_bf16(Whh[row * 256 + kf * 32 + q * 8 + j], hi, lo); vh[j] = hi; vl[j] = lo; }
      whhh[kf] = vh; whhl[kf] = vl;
    }
  }
  if (tid < 64) {
    int gate = tid >> 4, u = tid & 15;
    int grow = gate * 256 + U0 + u;
    sm->bias[tid] = bih[grow] + bhh[grow];
  }

  u64* own = bx_own + (size_t)g * OD * 4096;
  u64* src = (LAYER == 1) ? (bx_x + (size_t)g * 4 * 4096) : nullptr;
  unsigned* rfg    = rflag + g * 256;       // member m's flag at rfg[m*16]
  unsigned* rfself = rfg + mem * 16;

  float c = 0.f;

  for (int s = 0; s < T_; ++s) {
    // ---- layer0: fp32 x prefetch (issued early, overlaps spins) ----
    float xv[8];
    if (LAYER == 0) {
      const float* px = xin + ((size_t)(B0 + bb) * T_ + s) * 128 + uu * 8;
      float4 v0 = *(const float4*)px, v1 = *(const float4*)(px + 4);
      xv[0] = v0.x; xv[1] = v0.y; xv[2] = v0.z; xv[3] = v0.w;
      xv[4] = v1.x; xv[5] = v1.y; xv[6] = v1.z; xv[7] = v1.w;
    }

    // ---- layer0: rflag PREFETCH (evaluated just before publish; the agent
    //      load RT hides under the whole step). Needed only for s>=4. ----
    unsigned rfv = 0xffffffffu;
    if (LAYER == 0 && s >= 4 && w == 0 && lane < 16)
      rfv = __hip_atomic_load(&rfg[lane * 16], __ATOMIC_RELAXED, __HIP_MEMORY_SCOPE_AGENT);

    // ---- layer1: x PREFETCH (L0 runs ahead; verify after the h spin) ----
    u64 xp[16];
    if (LAYER == 1) {
      const u64* pbx = src + (size_t)(s & 3) * 4096;
      #pragma unroll
      for (int i = 0; i < 16; ++i)
        xp[i] = __hip_atomic_load(&pbx[i * 256 + tid], __ATOMIC_RELAXED, __HIP_MEMORY_SCOPE_AGENT);
    }

    // ---- spin-consume own group's h_{s-1} (the fundamental RT) ----
    if (s > 0) {
      const u64* pbh = own + (size_t)((s - 1) & (OD - 1)) * 4096;
      const unsigned htag = (unsigned)s;
      u64 hv64[16]; int it = 0;
      for (;;) {
        bool ok = true;
        #pragma unroll
        for (int i = 0; i < 16; ++i)
          hv64[i] = __hip_atomic_load(&pbh[i * 256 + tid], __ATOMIC_RELAXED, __HIP_MEMORY_SCOPE_AGENT);
        #pragma unroll
        for (int i = 0; i < 16; ++i) ok &= ((unsigned)(hv64[i] >> 32) == htag);
        if (ok) break;
        if (++it >= 50000) break;          // no-hang safety
        __builtin_amdgcn_s_sleep(1);
      }
      #pragma unroll
      for (int i = 0; i < 16; ++i) {
        unsigned d = (unsigned)hv64[i];
        sm->hhi[i][tid] = (short)(d >> 16);
        sm->hlo[i][tid] = (short)(d & 0xffffu);
      }
    } else {
      #pragma unroll
      for (int i = 0; i < 16; ++i) { sm->hhi[i][tid] = 0; sm->hlo[i][tid] = 0; }
    }

    // ---- layer1: verify prefetched x tags; rare-miss fallback spin ----
    if (LAYER == 1) {
      const u64* pbx = src + (size_t)(s & 3) * 4096;
      const unsigned xtag = (unsigned)(s + 1);
      bool ok = true;
      #pragma unroll
      for (int i = 0; i < 16; ++i) ok &= ((unsigned)(xp[i] >> 32) == xtag);
      if (!ok) {
        int it = 0;
        for (;;) {
          ok = true;
          #pragma unroll
          for (int i = 0; i < 16; ++i)
            xp[i] = __hip_atomic_load(&pbx[i * 256 + tid], __ATOMIC_RELAXED, __HIP_MEMORY_SCOPE_AGENT);
          #pragma unroll
          for (int i = 0; i < 16; ++i) ok &= ((unsigned)(xp[i] >> 32) == xtag);
          if (ok) break;
          if (++it >= 50000) break;        // no-hang safety
          __builtin_amdgcn_s_sleep(1);
        }
      }
      #pragma unroll
      for (int i = 0; i < 16; ++i) {
        unsigned d = (unsigned)xp[i];
        sm->xhi[i][tid] = (short)(d >> 16);
        sm->xlo[i][tid] = (short)(d & 0xffffu);
      }
    }

    // ---- layer0: stage fp32 x as bf16 hi/lo ----
    if (LAYER == 0) {
      s8v vh, vl;
      #pragma unroll
      for (int j = 0; j < 8; ++j) { short hi, lo; split_bf16(xv[j], hi, lo); vh[j] = hi; vl[j] = lo; }
      *(s8v*)&sm->xhi[bb][uu * 8] = vh;
      *(s8v*)&sm->xlo[bb][uu * 8] = vl;
    }
    __syncthreads();

    // layer1: publish read-progress (all threads' loads completed at barrier)
    if (LAYER == 1 && tid == 0)
      __hip_atomic_store(rfself, (unsigned)(s + 1), __ATOMIC_RELAXED, __HIP_MEMORY_SCOPE_AGENT);

    // ---- bf16x3 MFMA: hi*hi + lo*hi + hi*lo chains ----
    f4v a0 = {0.f, 0.f, 0.f, 0.f}, a1 = a0, a2 = a0;
    #pragma unroll
    for (int kf = 0; kf < NKX; ++kf) {
      s8v ah = *(const s8v*)&sm->xhi[n][kf * 32 + q * 8];
      s8v al = *(const s8v*)&sm->xlo[n][kf * 32 + q * 8];
      a0 = mfma16x16x32(ah, wxh[kf], a0);
      a1 = mfma16x16x32(al, wxh[kf], a1);
      a2 = mfma16x16x32(ah, wxl[kf], a2);
    }
    #pragma unroll
    for (int kf = 0; kf < 8; ++kf) {
      s8v ah = *(const s8v*)&sm->hhi[n][kf * 32 + q * 8];
      s8v al = *(const s8v*)&sm->hlo[n][kf * 32 + q * 8];
      a0 = mfma16x16x32(ah, whhh[kf], a0);
      a1 = mfma16x16x32(al, whhh[kf], a1);
      a2 = mfma16x16x32(ah, whhl[kf], a2);
    }
    f4v D = a0 + (a1 + a2);
    #pragma unroll
    for (int r = 0; r < 4; ++r) sm->gl[w][q * 4 + r][n] = D[r];
    __syncthreads();

    // ---- activations + state ----
    float pi = sm->gl[0][bb][uu] + sm->bias[uu];
    float pf = sm->gl[1][bb][uu] + sm->bias[16 + uu];
    float pg = sm->gl[2][bb][uu] + sm->bias[32 + uu];
    float po = sm->gl[3][bb][uu] + sm->bias[48 + uu];
    float ig = sig_(pi), fg = sig_(pf), gg = th_(pg), og = sig_(po);
    c = fg * c + ig * gg;
    float h = og * th_(c);

    // ---- layer0: evaluate prefetched back-pressure (RT already hidden).
    //      Publishing step s overwrites x(s-4): need rflag >= s-3. ----
    if (LAYER == 0) {
      if (s >= 4 && w == 0) {
        const unsigned tgt = (unsigned)(s - 3);
        bool ok = (lane < 16) ? (rfv >= tgt) : true;
        if (!__all((int)ok)) {
          int it = 0;
          for (;;) {
            unsigned v = (lane < 16)
              ? __hip_atomic_load(&rfg[lane * 16], __ATOMIC_RELAXED, __HIP_MEMORY_SCOPE_AGENT)
              : tgt;
            if (__all((int)(v >= tgt))) break;
            if (++it >= 50000) break;
            __builtin_amdgcn_s_sleep(1);
          }
        }
      }
      __syncthreads();
    }

    // ---- publish h (tagged, fire-and-forget) ----
    u64 val = ((u64)(unsigned)(s + 1) << 32) | (u64)pack_hilo(h);
    __hip_atomic_store(&own[(size_t)(s & (OD - 1)) * 4096 + bb * 256 + U0 + uu], val,
                       __ATOMIC_RELAXED, __HIP_MEMORY_SCOPE_AGENT);

    if (LAYER == 1 && s == T_ - 1)
      h1l[(B0 + bb) * H_ + U0 + uu] = h;
  }
}

__global__ __launch_bounds__(256, 2) void lstm_fused(
    const float* __restrict__ x,
    const float* __restrict__ Wih0, const float* __restrict__ Whh0,
    const float* __restrict__ bih0, const float* __restrict__ bhh0,
    const float* __restrict__ Wih1, const float* __restrict__ Whh1,
    const float* __restrict__ bih1, const float* __restrict__ bhh1,
    u64* bx0, u64* bx1, unsigned* rflag, float* h1l)
{
  __shared__ SMem sm;
  const int bid = blockIdx.x;
  if (bid < 256) {
    lstm_body<0>(&sm, x, Wih0, Whh0, bih0, bhh0, nullptr, bx0, rflag, nullptr,
                 bid >> 4, bid & 15);
  } else {
    const int b = bid - 256;
    lstm_body<1>(&sm, nullptr, Wih1, Whh1, bih1, bhh1, bx0, bx1, rflag, h1l,
                 b >> 4, b & 15);
  }
}

__global__ void fc_kernel(const float* __restrict__ h1l, const float* __restrict__ Wfc,
                          float* __restrict__ out) {
  __shared__ float hs[H_];
  const int b = blockIdx.x, o = threadIdx.x;
  hs[o]       = h1l[b * H_ + o];
  hs[o + 128] = h1l[b * H_ + o + 128];
  __syncthreads();
  float acc = 0.f;
  #pragma unroll 8
  for (int u = 0; u < H_; u += 4) {
    float4 wv = *(const float4*)&Wfc[o * H_ + u];
    acc += wv.x * hs[u] + wv.y * hs[u + 1] + wv.z * hs[u + 2] + wv.w * hs[u + 3];
  }
  out[b * OUTD + o] = acc;
}

extern "C" void kernel_launch(void* const* d_in, const int* in_sizes, int n_in,
                              void* d_out, int out_size, void* d_ws, size_t ws_size,
                              hipStream_t stream) {
  const float* x    = (const float*)d_in[0];
  const float* Wih0 = (const float*)d_in[1];
  const float* Whh0 = (const float*)d_in[2];
  const float* bih0 = (const float*)d_in[3];
  const float* bhh0 = (const float*)d_in[4];
  const float* Wih1 = (const float*)d_in[5];
  const float* Whh1 = (const float*)d_in[6];
  const float* bih1 = (const float*)d_in[7];
  const float* bhh1 = (const float*)d_in[8];
  const float* Wfc  = (const float*)d_in[9];

  // ws layout: bx0 (2 MiB, depth 4) | bx1 (1 MiB, depth 2) | rflag (16 KiB) |
  //            h1l (256 KiB)
  u64*      bx0   = (u64*)d_ws;                 // 16*4*4096
  u64*      bx1   = bx0 + 262144;               // 16*2*4096
  unsigned* rflag = (unsigned*)(bx1 + 131072);  // 16*16*16
  float*    h1l   = (float*)(rflag + 4096);     // 256*256

  // rflag must start at 0 (poison 0xAA.. would spoof the >= back-pressure check;
  // exchange tags use equality so poison can never match them).
  hipMemsetAsync(rflag, 0, 4096 * sizeof(unsigned), stream);

  lstm_fused<<<512, 256, 0, stream>>>(x, Wih0, Whh0, bih0, bhh0,
                                      Wih1, Whh1, bih1, bhh1,
                                      bx0, bx1, rflag, h1l);
  fc_kernel<<<256, 128, 0, stream>>>(h1l, Wfc, (float*)d_out);
}

// Round 4
// 2456.259 us; speedup vs baseline: 1.7507x; 1.1337x over previous
//
#include <hip/hip_runtime.h>
#include <stdint.h>

#define T_   512
#define H_   256
#define OUTD 128

typedef unsigned long long u64;
typedef __attribute__((ext_vector_type(8))) short s8v;
typedef __attribute__((ext_vector_type(4))) float f4v;

__device__ __forceinline__ f4v mfma16x16x32(s8v a, s8v b, f4v c) {
  return __builtin_amdgcn_mfma_f32_16x16x32_bf16(a, b, c, 0, 0, 0);
}

// fp32 -> bf16 hi (truncate) + bf16 lo (RN of remainder)
__device__ __forceinline__ void split_bf16(float f, short &hi, short &lo) {
  unsigned u  = __float_as_uint(f);
  unsigned uh = u & 0xffff0000u;
  hi = (short)(uh >> 16);
  float r = f - __uint_as_float(uh);
  unsigned ur = __float_as_uint(r);
  lo = (short)((ur + 0x7fffu + ((ur >> 16) & 1u)) >> 16);
}

__device__ __forceinline__ unsigned pack_hilo(float f) {
  short hi, lo; split_bf16(f, hi, lo);
  return ((unsigned)(unsigned short)hi << 16) | (unsigned)(unsigned short)lo;
}

__device__ __forceinline__ float sig_(float x) { return 1.f / (1.f + __expf(-x)); }
__device__ __forceinline__ float th_(float x)  { float e = __expf(2.f * x); return 1.f - 2.f / (e + 1.f); }

struct SMem {
  short xhi[16][264], xlo[16][264];
  short hhi[16][264], hlo[16][264];
  float gl[4][16][33];
  float bias[128];
};  // ~42.8 KB (1 block/CU)

// PARTITION CHANGE vs round 3 (protocol identical): 32 units/member ->
// 8 members/group, 128 blocks/layer, 256 blocks total = 1 block/CU.
// Rationale: step period is set by the straggler of the producer set,
// re-synchronized every step; halving fan-in (16->8) and removing 2-blocks/CU
// phase interference attacks the straggler directly. Weights stay in VGPRs
// (L1: 256 VGPR weights; __launch_bounds__(256,1) allows 512/wave).
//
// Exchange protocol: entry = u64 (tag<<32 | bf16hi<<16 | bf16lo), tag = step+1.
// bx0 (layer0 h / layer1 x) depth-4 (slot = s&3); bx1 (layer1 own) depth-2.
// Tag-equality spin on exactly the data each thread consumes (8B atomicity =>
// tag/data consistent). Own-group recurrence self-synchronizing at depth>=2.
// L0 publishing step s overwrites x(s-4) => needs rflag >= s-3; rflag is
// PREFETCHED at step top, evaluated before publish (RT hidden under step).
// L1's x(s) prefetched before the h-spin, verified after (RT hidden under h RT).
template <int LAYER>
__device__ __forceinline__ void lstm_body(
    SMem* sm,
    const float* __restrict__ xin,
    const float* __restrict__ Wih, const float* __restrict__ Whh,
    const float* __restrict__ bih, const float* __restrict__ bhh,
    u64* bx_x,        // LAYER==1: consumed exchange (layer0 h, depth 4)
    u64* bx_own,      // produced exchange (L0: bx0 depth 4; L1: bx1 depth 2)
    unsigned* rflag,  // [16 groups][8 members], stride 16 dwords
    float* h1l,       // LAYER==1: last h out [256,256]
    int g, int mem)
{
  constexpr int KX  = (LAYER == 0) ? 128 : 256;
  constexpr int NKX = KX / 32;
  constexpr int OD  = (LAYER == 0) ? 4 : 2;   // own exchange depth
  const int tid = threadIdx.x;
  const int w = tid >> 6, lane = tid & 63, n = lane & 15, q = lane >> 4;
  const int bb = tid >> 4, uu = tid & 15;
  const int B0 = g * 16, U0 = mem * 32;

  // ---- weight slice -> register B-fragments (bf16 hi/lo), once ----
  // wave w = gate w; 2 N-tiles of 16 units each (t=0,1)
  s8v wxh[2][NKX], wxl[2][NKX], whhh[2][8], whhl[2][8];
  #pragma unroll
  for (int t = 0; t < 2; ++t) {
    const int row = w * 256 + U0 + t * 16 + n;
    #pragma unroll
    for (int kf = 0; kf < NKX; ++kf) {
      s8v vh, vl;
      #pragma unroll
      for (int j = 0; j < 8; ++j) { short hi, lo; split_bf16(Wih[row * KX + kf * 32 + q * 8 + j], hi, lo); vh[j] = hi; vl[j] = lo; }
      wxh[t][kf] = vh; wxl[t][kf] = vl;
    }
    #pragma unroll
    for (int kf = 0; kf < 8; ++kf) {
      s8v vh, vl;
      #pragma unroll
      for (int j = 0; j < 8; ++j) { short hi, lo; split_bf16(Whh[row * 256 + kf * 32 + q * 8 + j], hi, lo); vh[j] = hi; vl[j] = lo; }
      whhh[t][kf] = vh; whhl[t][kf] = vl;
    }
  }
  if (tid < 128) {
    int gate = tid >> 5, u = tid & 31;
    int grow = gate * 256 + U0 + u;
    sm->bias[tid] = bih[grow] + bhh[grow];
  }

  u64* own = bx_own + (size_t)g * OD * 4096;
  u64* src = (LAYER == 1) ? (bx_x + (size_t)g * 4 * 4096) : nullptr;
  unsigned* rfg    = rflag + g * 128;       // member m's flag at rfg[m*16]
  unsigned* rfself = rfg + mem * 16;

  float c0 = 0.f, c1 = 0.f;

  for (int s = 0; s < T_; ++s) {
    // ---- layer0: fp32 x prefetch (issued early, overlaps spins) ----
    float xv[8];
    if (LAYER == 0) {
      const float* px = xin + ((size_t)(B0 + bb) * T_ + s) * 128 + uu * 8;
      float4 v0 = *(const float4*)px, v1 = *(const float4*)(px + 4);
      xv[0] = v0.x; xv[1] = v0.y; xv[2] = v0.z; xv[3] = v0.w;
      xv[4] = v1.x; xv[5] = v1.y; xv[6] = v1.z; xv[7] = v1.w;
    }

    // ---- layer0: rflag PREFETCH (evaluated just before publish) ----
    unsigned rfv = 0xffffffffu;
    if (LAYER == 0 && s >= 4 && w == 0 && lane < 8)
      rfv = __hip_atomic_load(&rfg[lane * 16], __ATOMIC_RELAXED, __HIP_MEMORY_SCOPE_AGENT);

    // ---- layer1: x PREFETCH (L0 runs ahead; verify after the h spin) ----
    u64 xp[16];
    if (LAYER == 1) {
      const u64* pbx = src + (size_t)(s & 3) * 4096;
      #pragma unroll
      for (int i = 0; i < 16; ++i)
        xp[i] = __hip_atomic_load(&pbx[i * 256 + tid], __ATOMIC_RELAXED, __HIP_MEMORY_SCOPE_AGENT);
    }

    // ---- spin-consume own group's h_{s-1} (the fundamental RT) ----
    if (s > 0) {
      const u64* pbh = own + (size_t)((s - 1) & (OD - 1)) * 4096;
      const unsigned htag = (unsigned)s;
      u64 hv64[16]; int it = 0;
      for (;;) {
        bool ok = true;
        #pragma unroll
        for (int i = 0; i < 16; ++i)
          hv64[i] = __hip_atomic_load(&pbh[i * 256 + tid], __ATOMIC_RELAXED, __HIP_MEMORY_SCOPE_AGENT);
        #pragma unroll
        for (int i = 0; i < 16; ++i) ok &= ((unsigned)(hv64[i] >> 32) == htag);
        if (ok) break;
        if (++it >= 50000) break;          // no-hang safety
        __builtin_amdgcn_s_sleep(1);
      }
      #pragma unroll
      for (int i = 0; i < 16; ++i) {
        unsigned d = (unsigned)hv64[i];
        sm->hhi[i][tid] = (short)(d >> 16);
        sm->hlo[i][tid] = (short)(d & 0xffffu);
      }
    } else {
      #pragma unroll
      for (int i = 0; i < 16; ++i) { sm->hhi[i][tid] = 0; sm->hlo[i][tid] = 0; }
    }

    // ---- layer1: verify prefetched x tags; rare-miss fallback spin ----
    if (LAYER == 1) {
      const u64* pbx = src + (size_t)(s & 3) * 4096;
      const unsigned xtag = (unsigned)(s + 1);
      bool ok = true;
      #pragma unroll
      for (int i = 0; i < 16; ++i) ok &= ((unsigned)(xp[i] >> 32) == xtag);
      if (!ok) {
        int it = 0;
        for (;;) {
          ok = true;
          #pragma unroll
          for (int i = 0; i < 16; ++i)
            xp[i] = __hip_atomic_load(&pbx[i * 256 + tid], __ATOMIC_RELAXED, __HIP_MEMORY_SCOPE_AGENT);
          #pragma unroll
          for (int i = 0; i < 16; ++i) ok &= ((unsigned)(xp[i] >> 32) == xtag);
          if (ok) break;
          if (++it >= 50000) break;        // no-hang safety
          __builtin_amdgcn_s_sleep(1);
        }
      }
      #pragma unroll
      for (int i = 0; i < 16; ++i) {
        unsigned d = (unsigned)xp[i];
        sm->xhi[i][tid] = (short)(d >> 16);
        sm->xlo[i][tid] = (short)(d & 0xffffu);
      }
    }

    // ---- layer0: stage fp32 x as bf16 hi/lo ----
    if (LAYER == 0) {
      s8v vh, vl;
      #pragma unroll
      for (int j = 0; j < 8; ++j) { short hi, lo; split_bf16(xv[j], hi, lo); vh[j] = hi; vl[j] = lo; }
      *(s8v*)&sm->xhi[bb][uu * 8] = vh;
      *(s8v*)&sm->xlo[bb][uu * 8] = vl;
    }
    __syncthreads();

    // layer1: publish read-progress (all threads' loads completed at barrier)
    if (LAYER == 1 && tid == 0)
      __hip_atomic_store(rfself, (unsigned)(s + 1), __ATOMIC_RELAXED, __HIP_MEMORY_SCOPE_AGENT);

    // ---- bf16x3 MFMA, 2 N-tiles per wave: hi*hi + lo*hi + hi*lo ----
    f4v a00 = {0.f,0.f,0.f,0.f}, a01 = a00, a02 = a00;
    f4v a10 = a00, a11 = a00, a12 = a00;
    #pragma unroll
    for (int kf = 0; kf < NKX; ++kf) {
      s8v ah = *(const s8v*)&sm->xhi[n][kf * 32 + q * 8];
      s8v al = *(const s8v*)&sm->xlo[n][kf * 32 + q * 8];
      a00 = mfma16x16x32(ah, wxh[0][kf], a00);
      a01 = mfma16x16x32(al, wxh[0][kf], a01);
      a02 = mfma16x16x32(ah, wxl[0][kf], a02);
      a10 = mfma16x16x32(ah, wxh[1][kf], a10);
      a11 = mfma16x16x32(al, wxh[1][kf], a11);
      a12 = mfma16x16x32(ah, wxl[1][kf], a12);
    }
    #pragma unroll
    for (int kf = 0; kf < 8; ++kf) {
      s8v ah = *(const s8v*)&sm->hhi[n][kf * 32 + q * 8];
      s8v al = *(const s8v*)&sm->hlo[n][kf * 32 + q * 8];
      a00 = mfma16x16x32(ah, whhh[0][kf], a00);
      a01 = mfma16x16x32(al, whhh[0][kf], a01);
      a02 = mfma16x16x32(ah, whhl[0][kf], a02);
      a10 = mfma16x16x32(ah, whhh[1][kf], a10);
      a11 = mfma16x16x32(al, whhh[1][kf], a11);
      a12 = mfma16x16x32(ah, whhl[1][kf], a12);
    }
    f4v D0 = a00 + (a01 + a02);
    f4v D1 = a10 + (a11 + a12);
    #pragma unroll
    for (int r = 0; r < 4; ++r) {
      sm->gl[w][q * 4 + r][n]      = D0[r];
      sm->gl[w][q * 4 + r][16 + n] = D1[r];
    }
    __syncthreads();

    // ---- activations + state (2 units per thread: uu and uu+16) ----
    float h0v, h1v;
    {
      float pi = sm->gl[0][bb][uu] + sm->bias[uu];
      float pf = sm->gl[1][bb][uu] + sm->bias[32 + uu];
      float pg = sm->gl[2][bb][uu] + sm->bias[64 + uu];
      float po = sm->gl[3][bb][uu] + sm->bias[96 + uu];
      float ig = sig_(pi), fg = sig_(pf), gg = th_(pg), og = sig_(po);
      c0 = fg * c0 + ig * gg;
      h0v = og * th_(c0);
    }
    {
      int u = uu + 16;
      float pi = sm->gl[0][bb][u] + sm->bias[u];
      float pf = sm->gl[1][bb][u] + sm->bias[32 + u];
      float pg = sm->gl[2][bb][u] + sm->bias[64 + u];
      float po = sm->gl[3][bb][u] + sm->bias[96 + u];
      float ig = sig_(pi), fg = sig_(pf), gg = th_(pg), og = sig_(po);
      c1 = fg * c1 + ig * gg;
      h1v = og * th_(c1);
    }

    // ---- layer0: evaluate prefetched back-pressure (RT already hidden).
    //      Publishing step s overwrites x(s-4): need rflag >= s-3. ----
    if (LAYER == 0) {
      if (s >= 4 && w == 0) {
        const unsigned tgt = (unsigned)(s - 3);
        bool ok = (lane < 8) ? (rfv >= tgt) : true;
        if (!__all((int)ok)) {
          int it = 0;
          for (;;) {
            unsigned v = (lane < 8)
              ? __hip_atomic_load(&rfg[lane * 16], __ATOMIC_RELAXED, __HIP_MEMORY_SCOPE_AGENT)
              : tgt;
            if (__all((int)(v >= tgt))) break;
            if (++it >= 50000) break;
            __builtin_amdgcn_s_sleep(1);
          }
        }
      }
      __syncthreads();
    }

    // ---- publish h (tagged, fire-and-forget; 2 entries/thread) ----
    const u64 tagw = (u64)(unsigned)(s + 1) << 32;
    u64* slot = own + (size_t)(s & (OD - 1)) * 4096 + bb * 256 + U0 + uu;
    __hip_atomic_store(slot,      tagw | (u64)pack_hilo(h0v), __ATOMIC_RELAXED, __HIP_MEMORY_SCOPE_AGENT);
    __hip_atomic_store(slot + 16, tagw | (u64)pack_hilo(h1v), __ATOMIC_RELAXED, __HIP_MEMORY_SCOPE_AGENT);

    if (LAYER == 1 && s == T_ - 1) {
      h1l[(B0 + bb) * H_ + U0 + uu]      = h0v;
      h1l[(B0 + bb) * H_ + U0 + 16 + uu] = h1v;
    }
  }
}

__global__ __launch_bounds__(256, 1) void lstm_fused(
    const float* __restrict__ x,
    const float* __restrict__ Wih0, const float* __restrict__ Whh0,
    const float* __restrict__ bih0, const float* __restrict__ bhh0,
    const float* __restrict__ Wih1, const float* __restrict__ Whh1,
    const float* __restrict__ bih1, const float* __restrict__ bhh1,
    u64* bx0, u64* bx1, unsigned* rflag, float* h1l)
{
  __shared__ SMem sm;
  const int bid = blockIdx.x;
  if (bid < 128) {
    lstm_body<0>(&sm, x, Wih0, Whh0, bih0, bhh0, nullptr, bx0, rflag, nullptr,
                 bid >> 3, bid & 7);
  } else {
    const int b = bid - 128;
    lstm_body<1>(&sm, nullptr, Wih1, Whh1, bih1, bhh1, bx0, bx1, rflag, h1l,
                 b >> 3, b & 7);
  }
}

__global__ void fc_kernel(const float* __restrict__ h1l, const float* __restrict__ Wfc,
                          float* __restrict__ out) {
  __shared__ float hs[H_];
  const int b = blockIdx.x, o = threadIdx.x;
  hs[o]       = h1l[b * H_ + o];
  hs[o + 128] = h1l[b * H_ + o + 128];
  __syncthreads();
  float acc = 0.f;
  #pragma unroll 8
  for (int u = 0; u < H_; u += 4) {
    float4 wv = *(const float4*)&Wfc[o * H_ + u];
    acc += wv.x * hs[u] + wv.y * hs[u + 1] + wv.z * hs[u + 2] + wv.w * hs[u + 3];
  }
  out[b * OUTD + o] = acc;
}

extern "C" void kernel_launch(void* const* d_in, const int* in_sizes, int n_in,
                              void* d_out, int out_size, void* d_ws, size_t ws_size,
                              hipStream_t stream) {
  const float* x    = (const float*)d_in[0];
  const float* Wih0 = (const float*)d_in[1];
  const float* Whh0 = (const float*)d_in[2];
  const float* bih0 = (const float*)d_in[3];
  const float* bhh0 = (const float*)d_in[4];
  const float* Wih1 = (const float*)d_in[5];
  const float* Whh1 = (const float*)d_in[6];
  const float* bih1 = (const float*)d_in[7];
  const float* bhh1 = (const float*)d_in[8];
  const float* Wfc  = (const float*)d_in[9];

  // ws layout: bx0 (2 MiB, depth 4) | bx1 (1 MiB, depth 2) | rflag (16 KiB) |
  //            h1l (256 KiB)
  u64*      bx0   = (u64*)d_ws;                 // 16*4*4096
  u64*      bx1   = bx0 + 262144;               // 16*2*4096
  unsigned* rflag = (unsigned*)(bx1 + 131072);  // 16*8*16 used
  float*    h1l   = (float*)(rflag + 4096);     // 256*256

  // rflag must start at 0 (poison 0xAA.. would spoof the >= back-pressure check;
  // exchange tags use equality so poison can never match them).
  hipMemsetAsync(rflag, 0, 4096 * sizeof(unsigned), stream);

  lstm_fused<<<256, 256, 0, stream>>>(x, Wih0, Whh0, bih0, bhh0,
                                      Wih1, Whh1, bih1, bhh1,
                                      bx0, bx1, rflag, h1l);
  fc_kernel<<<256, 128, 0, stream>>>(h1l, Wfc, (float*)d_out);
}

// Round 5
// 2431.951 us; speedup vs baseline: 1.7682x; 1.0100x over previous
//
#include <hip/hip_runtime.h>
#include <stdint.h>

#define T_   512
#define H_   256
#define OUTD 128

typedef unsigned long long u64;
typedef __attribute__((ext_vector_type(8))) short s8v;
typedef __attribute__((ext_vector_type(4))) float f4v;
typedef __attribute__((ext_vector_type(4))) unsigned u4v;

__device__ __forceinline__ f4v mfma16x16x32(s8v a, s8v b, f4v c) {
  return __builtin_amdgcn_mfma_f32_16x16x32_bf16(a, b, c, 0, 0, 0);
}

// fp32 -> bf16 hi (truncate) + bf16 lo (RN of remainder)
__device__ __forceinline__ void split_bf16(float f, short &hi, short &lo) {
  unsigned u  = __float_as_uint(f);
  unsigned uh = u & 0xffff0000u;
  hi = (short)(uh >> 16);
  float r = f - __uint_as_float(uh);
  unsigned ur = __float_as_uint(r);
  lo = (short)((ur + 0x7fffu + ((ur >> 16) & 1u)) >> 16);
}

__device__ __forceinline__ unsigned pack_hilo(float f) {
  short hi, lo; split_bf16(f, hi, lo);
  return ((unsigned)(unsigned short)hi << 16) | (unsigned)(unsigned short)lo;
}

// 8 packed dwords (hi16|lo16) -> s8v of 8 hi-bf16 and s8v of 8 lo-bf16
__device__ __forceinline__ void unpk(u4v A, u4v B, s8v &hi, s8v &lo) {
  union U { unsigned u[4]; s8v v; };
  U H, L;
  H.u[0] = __builtin_amdgcn_perm(A.y, A.x, 0x07060302u);
  H.u[1] = __builtin_amdgcn_perm(A.w, A.z, 0x07060302u);
  H.u[2] = __builtin_amdgcn_perm(B.y, B.x, 0x07060302u);
  H.u[3] = __builtin_amdgcn_perm(B.w, B.z, 0x07060302u);
  L.u[0] = __builtin_amdgcn_perm(A.y, A.x, 0x05040100u);
  L.u[1] = __builtin_amdgcn_perm(A.w, A.z, 0x05040100u);
  L.u[2] = __builtin_amdgcn_perm(B.y, B.x, 0x05040100u);
  L.u[3] = __builtin_amdgcn_perm(B.w, B.z, 0x05040100u);
  hi = H.v; lo = L.v;
}

__device__ __forceinline__ float sig_(float x) { return 1.f / (1.f + __expf(-x)); }
__device__ __forceinline__ float th_(float x)  { float e = __expf(2.f * x); return 1.f - 2.f / (e + 1.f); }

// Staging is PACKED (hi16|lo16) dwords — exactly the exchange payload, so the
// spin's low dword is stored verbatim (16 ds_write_b32 vs 32 ds_write_b16:
// halves write instrs AND kills same-dword half-write bank merges, which
// accounted for ~2.9k conflict-cy/step/CU in round 4's counters).
// Row stride 268 dwords (=12 mod 32 banks) keeps b128 reads AND the L0 x
// 16B writes evenly spread at the 8-lanes-per-4-bank-group minimum.
struct SMem {
  unsigned xpk[16][268];
  unsigned hpk[16][268];
  float gl[4][16][33];
  float bias[128];
};  // ~43.3 KB (1 block/CU)

// Partition (round 4): 32 units/member, 8 members/group, 16 groups/layer,
// 256 blocks total = 1 block/CU. Weights register-resident.
// Exchange protocol: entry = u64 (tag<<32 | bf16hi<<16 | bf16lo), tag = step+1.
// bx0 (layer0 h / layer1 x) depth-4 (slot = s&3); bx1 (layer1 own) depth-2.
// Tag-equality spin on exactly the data each thread consumes (8B atomicity =>
// tag/data consistent). Own-group recurrence self-synchronizing at depth>=2.
// L0 publishing step s overwrites x(s-4) => needs rflag >= s-3; rflag is
// PREFETCHED at step top, evaluated before publish (RT hidden under step).
// L1's x(s) prefetched before the h-spin, verified after (RT hidden under h RT).
template <int LAYER>
__device__ __forceinline__ void lstm_body(
    SMem* sm,
    const float* __restrict__ xin,
    const float* __restrict__ Wih, const float* __restrict__ Whh,
    const float* __restrict__ bih, const float* __restrict__ bhh,
    u64* bx_x,        // LAYER==1: consumed exchange (layer0 h, depth 4)
    u64* bx_own,      // produced exchange (L0: bx0 depth 4; L1: bx1 depth 2)
    unsigned* rflag,  // [16 groups][8 members], stride 16 dwords
    float* h1l,       // LAYER==1: last h out [256,256]
    int g, int mem)
{
  constexpr int KX  = (LAYER == 0) ? 128 : 256;
  constexpr int NKX = KX / 32;
  constexpr int OD  = (LAYER == 0) ? 4 : 2;   // own exchange depth
  const int tid = threadIdx.x;
  const int w = tid >> 6, lane = tid & 63, n = lane & 15, q = lane >> 4;
  const int bb = tid >> 4, uu = tid & 15;
  const int B0 = g * 16, U0 = mem * 32;

  // ---- weight slice -> register B-fragments (bf16 hi/lo), once ----
  // wave w = gate w; 2 N-tiles of 16 units each (t=0,1)
  s8v wxh[2][NKX], wxl[2][NKX], whhh[2][8], whhl[2][8];
  #pragma unroll
  for (int t = 0; t < 2; ++t) {
    const int row = w * 256 + U0 + t * 16 + n;
    #pragma unroll
    for (int kf = 0; kf < NKX; ++kf) {
      s8v vh, vl;
      #pragma unroll
      for (int j = 0; j < 8; ++j) { short hi, lo; split_bf16(Wih[row * KX + kf * 32 + q * 8 + j], hi, lo); vh[j] = hi; vl[j] = lo; }
      wxh[t][kf] = vh; wxl[t][kf] = vl;
    }
    #pragma unroll
    for (int kf = 0; kf < 8; ++kf) {
      s8v vh, vl;
      #pragma unroll
      for (int j = 0; j < 8; ++j) { short hi, lo; split_bf16(Whh[row * 256 + kf * 32 + q * 8 + j], hi, lo); vh[j] = hi; vl[j] = lo; }
      whhh[t][kf] = vh; whhl[t][kf] = vl;
    }
  }
  if (tid < 128) {
    int gate = tid >> 5, u = tid & 31;
    int grow = gate * 256 + U0 + u;
    sm->bias[tid] = bih[grow] + bhh[grow];
  }

  u64* own = bx_own + (size_t)g * OD * 4096;
  u64* src = (LAYER == 1) ? (bx_x + (size_t)g * 4 * 4096) : nullptr;
  unsigned* rfg    = rflag + g * 128;       // member m's flag at rfg[m*16]
  unsigned* rfself = rfg + mem * 16;

  float c0 = 0.f, c1 = 0.f;

  for (int s = 0; s < T_; ++s) {
    // ---- layer0: fp32 x prefetch (issued early, overlaps spins) ----
    float xv[8];
    if (LAYER == 0) {
      const float* px = xin + ((size_t)(B0 + bb) * T_ + s) * 128 + uu * 8;
      float4 v0 = *(const float4*)px, v1 = *(const float4*)(px + 4);
      xv[0] = v0.x; xv[1] = v0.y; xv[2] = v0.z; xv[3] = v0.w;
      xv[4] = v1.x; xv[5] = v1.y; xv[6] = v1.z; xv[7] = v1.w;
    }

    // ---- layer0: rflag PREFETCH (evaluated just before publish) ----
    unsigned rfv = 0xffffffffu;
    if (LAYER == 0 && s >= 4 && w == 0 && lane < 8)
      rfv = __hip_atomic_load(&rfg[lane * 16], __ATOMIC_RELAXED, __HIP_MEMORY_SCOPE_AGENT);

    // ---- layer1: x PREFETCH (L0 runs ahead; verify after the h spin) ----
    u64 xp[16];
    if (LAYER == 1) {
      const u64* pbx = src + (size_t)(s & 3) * 4096;
      #pragma unroll
      for (int i = 0; i < 16; ++i)
        xp[i] = __hip_atomic_load(&pbx[i * 256 + tid], __ATOMIC_RELAXED, __HIP_MEMORY_SCOPE_AGENT);
    }

    // ---- spin-consume own group's h_{s-1} (the fundamental RT) ----
    if (s > 0) {
      const u64* pbh = own + (size_t)((s - 1) & (OD - 1)) * 4096;
      const unsigned htag = (unsigned)s;
      u64 hv64[16]; int it = 0;
      for (;;) {
        bool ok = true;
        #pragma unroll
        for (int i = 0; i < 16; ++i)
          hv64[i] = __hip_atomic_load(&pbh[i * 256 + tid], __ATOMIC_RELAXED, __HIP_MEMORY_SCOPE_AGENT);
        #pragma unroll
        for (int i = 0; i < 16; ++i) ok &= ((unsigned)(hv64[i] >> 32) == htag);
        if (ok) break;
        if (++it >= 50000) break;          // no-hang safety
        __builtin_amdgcn_s_sleep(1);
      }
      #pragma unroll
      for (int i = 0; i < 16; ++i)
        sm->hpk[i][tid] = (unsigned)hv64[i];
    } else {
      #pragma unroll
      for (int i = 0; i < 16; ++i) sm->hpk[i][tid] = 0u;
    }

    // ---- layer1: verify prefetched x tags; rare-miss fallback spin ----
    if (LAYER == 1) {
      const u64* pbx = src + (size_t)(s & 3) * 4096;
      const unsigned xtag = (unsigned)(s + 1);
      bool ok = true;
      #pragma unroll
      for (int i = 0; i < 16; ++i) ok &= ((unsigned)(xp[i] >> 32) == xtag);
      if (!ok) {
        int it = 0;
        for (;;) {
          ok = true;
          #pragma unroll
          for (int i = 0; i < 16; ++i)
            xp[i] = __hip_atomic_load(&pbx[i * 256 + tid], __ATOMIC_RELAXED, __HIP_MEMORY_SCOPE_AGENT);
          #pragma unroll
          for (int i = 0; i < 16; ++i) ok &= ((unsigned)(xp[i] >> 32) == xtag);
          if (ok) break;
          if (++it >= 50000) break;        // no-hang safety
          __builtin_amdgcn_s_sleep(1);
        }
      }
      #pragma unroll
      for (int i = 0; i < 16; ++i)
        sm->xpk[i][tid] = (unsigned)xp[i];
    }

    // ---- layer0: stage fp32 x as packed bf16 hi|lo ----
    if (LAYER == 0) {
      unsigned dp[8];
      #pragma unroll
      for (int j = 0; j < 8; ++j) dp[j] = pack_hilo(xv[j]);
      u4v w0 = {dp[0], dp[1], dp[2], dp[3]};
      u4v w1 = {dp[4], dp[5], dp[6], dp[7]};
      *(u4v*)&sm->xpk[bb][uu * 8]     = w0;
      *(u4v*)&sm->xpk[bb][uu * 8 + 4] = w1;
    }
    __syncthreads();

    // layer1: publish read-progress (all threads' loads completed at barrier)
    if (LAYER == 1 && tid == 0)
      __hip_atomic_store(rfself, (unsigned)(s + 1), __ATOMIC_RELAXED, __HIP_MEMORY_SCOPE_AGENT);

    // ---- bf16x3 MFMA, 2 N-tiles per wave: hi*hi + lo*hi + hi*lo ----
    f4v a00 = {0.f,0.f,0.f,0.f}, a01 = a00, a02 = a00;
    f4v a10 = a00, a11 = a00, a12 = a00;
    #pragma unroll
    for (int kf = 0; kf < NKX; ++kf) {
      u4v A0 = *(const u4v*)&sm->xpk[n][kf * 32 + q * 8];
      u4v A1 = *(const u4v*)&sm->xpk[n][kf * 32 + q * 8 + 4];
      s8v ah, al; unpk(A0, A1, ah, al);
      a00 = mfma16x16x32(ah, wxh[0][kf], a00);
      a01 = mfma16x16x32(al, wxh[0][kf], a01);
      a02 = mfma16x16x32(ah, wxl[0][kf], a02);
      a10 = mfma16x16x32(ah, wxh[1][kf], a10);
      a11 = mfma16x16x32(al, wxh[1][kf], a11);
      a12 = mfma16x16x32(ah, wxl[1][kf], a12);
    }
    #pragma unroll
    for (int kf = 0; kf < 8; ++kf) {
      u4v A0 = *(const u4v*)&sm->hpk[n][kf * 32 + q * 8];
      u4v A1 = *(const u4v*)&sm->hpk[n][kf * 32 + q * 8 + 4];
      s8v ah, al; unpk(A0, A1, ah, al);
      a00 = mfma16x16x32(ah, whhh[0][kf], a00);
      a01 = mfma16x16x32(al, whhh[0][kf], a01);
      a02 = mfma16x16x32(ah, whhl[0][kf], a02);
      a10 = mfma16x16x32(ah, whhh[1][kf], a10);
      a11 = mfma16x16x32(al, whhh[1][kf], a11);
      a12 = mfma16x16x32(ah, whhl[1][kf], a12);
    }
    f4v D0 = a00 + (a01 + a02);
    f4v D1 = a10 + (a11 + a12);
    #pragma unroll
    for (int r = 0; r < 4; ++r) {
      sm->gl[w][q * 4 + r][n]      = D0[r];
      sm->gl[w][q * 4 + r][16 + n] = D1[r];
    }
    __syncthreads();

    // ---- activations + state (2 units per thread: uu and uu+16) ----
    float h0v, h1v;
    {
      float pi = sm->gl[0][bb][uu] + sm->bias[uu];
      float pf = sm->gl[1][bb][uu] + sm->bias[32 + uu];
      float pg = sm->gl[2][bb][uu] + sm->bias[64 + uu];
      float po = sm->gl[3][bb][uu] + sm->bias[96 + uu];
      float ig = sig_(pi), fg = sig_(pf), gg = th_(pg), og = sig_(po);
      c0 = fg * c0 + ig * gg;
      h0v = og * th_(c0);
    }
    {
      int u = uu + 16;
      float pi = sm->gl[0][bb][u] + sm->bias[u];
      float pf = sm->gl[1][bb][u] + sm->bias[32 + u];
      float pg = sm->gl[2][bb][u] + sm->bias[64 + u];
      float po = sm->gl[3][bb][u] + sm->bias[96 + u];
      float ig = sig_(pi), fg = sig_(pf), gg = th_(pg), og = sig_(po);
      c1 = fg * c1 + ig * gg;
      h1v = og * th_(c1);
    }

    // ---- layer0: evaluate prefetched back-pressure (RT already hidden).
    //      Publishing step s overwrites x(s-4): need rflag >= s-3. ----
    if (LAYER == 0) {
      if (s >= 4 && w == 0) {
        const unsigned tgt = (unsigned)(s - 3);
        bool ok = (lane < 8) ? (rfv >= tgt) : true;
        if (!__all((int)ok)) {
          int it = 0;
          for (;;) {
            unsigned v = (lane < 8)
              ? __hip_atomic_load(&rfg[lane * 16], __ATOMIC_RELAXED, __HIP_MEMORY_SCOPE_AGENT)
              : tgt;
            if (__all((int)(v >= tgt))) break;
            if (++it >= 50000) break;
            __builtin_amdgcn_s_sleep(1);
          }
        }
      }
      __syncthreads();
    }

    // ---- publish h (tagged, fire-and-forget; 2 entries/thread) ----
    const u64 tagw = (u64)(unsigned)(s + 1) << 32;
    u64* slot = own + (size_t)(s & (OD - 1)) * 4096 + bb * 256 + U0 + uu;
    __hip_atomic_store(slot,      tagw | (u64)pack_hilo(h0v), __ATOMIC_RELAXED, __HIP_MEMORY_SCOPE_AGENT);
    __hip_atomic_store(slot + 16, tagw | (u64)pack_hilo(h1v), __ATOMIC_RELAXED, __HIP_MEMORY_SCOPE_AGENT);

    if (LAYER == 1 && s == T_ - 1) {
      h1l[(B0 + bb) * H_ + U0 + uu]      = h0v;
      h1l[(B0 + bb) * H_ + U0 + 16 + uu] = h1v;
    }
  }
}

__global__ __launch_bounds__(256, 1) void lstm_fused(
    const float* __restrict__ x,
    const float* __restrict__ Wih0, const float* __restrict__ Whh0,
    const float* __restrict__ bih0, const float* __restrict__ bhh0,
    const float* __restrict__ Wih1, const float* __restrict__ Whh1,
    const float* __restrict__ bih1, const float* __restrict__ bhh1,
    u64* bx0, u64* bx1, unsigned* rflag, float* h1l)
{
  __shared__ SMem sm;
  const int bid = blockIdx.x;
  if (bid < 128) {
    lstm_body<0>(&sm, x, Wih0, Whh0, bih0, bhh0, nullptr, bx0, rflag, nullptr,
                 bid >> 3, bid & 7);
  } else {
    const int b = bid - 128;
    lstm_body<1>(&sm, nullptr, Wih1, Whh1, bih1, bhh1, bx0, bx1, rflag, h1l,
                 b >> 3, b & 7);
  }
}

__global__ void fc_kernel(const float* __restrict__ h1l, const float* __restrict__ Wfc,
                          float* __restrict__ out) {
  __shared__ float hs[H_];
  const int b = blockIdx.x, o = threadIdx.x;
  hs[o]       = h1l[b * H_ + o];
  hs[o + 128] = h1l[b * H_ + o + 128];
  __syncthreads();
  float acc = 0.f;
  #pragma unroll 8
  for (int u = 0; u < H_; u += 4) {
    float4 wv = *(const float4*)&Wfc[o * H_ + u];
    acc += wv.x * hs[u] + wv.y * hs[u + 1] + wv.z * hs[u + 2] + wv.w * hs[u + 3];
  }
  out[b * OUTD + o] = acc;
}

extern "C" void kernel_launch(void* const* d_in, const int* in_sizes, int n_in,
                              void* d_out, int out_size, void* d_ws, size_t ws_size,
                              hipStream_t stream) {
  const float* x    = (const float*)d_in[0];
  const float* Wih0 = (const float*)d_in[1];
  const float* Whh0 = (const float*)d_in[2];
  const float* bih0 = (const float*)d_in[3];
  const float* bhh0 = (const float*)d_in[4];
  const float* Wih1 = (const float*)d_in[5];
  const float* Whh1 = (const float*)d_in[6];
  const float* bih1 = (const float*)d_in[7];
  const float* bhh1 = (const float*)d_in[8];
  const float* Wfc  = (const float*)d_in[9];

  // ws layout: bx0 (2 MiB, depth 4) | bx1 (1 MiB, depth 2) | rflag (16 KiB) |
  //            h1l (256 KiB)
  u64*      bx0   = (u64*)d_ws;                 // 16*4*4096
  u64*      bx1   = bx0 + 262144;               // 16*2*4096
  unsigned* rflag = (unsigned*)(bx1 + 131072);  // 16*8*16 used
  float*    h1l   = (float*)(rflag + 4096);     // 256*256

  // rflag must start at 0 (poison 0xAA.. would spoof the >= back-pressure check;
  // exchange tags use equality so poison can never match them).
  hipMemsetAsync(rflag, 0, 4096 * sizeof(unsigned), stream);

  lstm_fused<<<256, 256, 0, stream>>>(x, Wih0, Whh0, bih0, bhh0,
                                      Wih1, Whh1, bih1, bhh1,
                                      bx0, bx1, rflag, h1l);
  fc_kernel<<<256, 128, 0, stream>>>(h1l, Wfc, (float*)d_out);
}

// Round 6
// 2348.451 us; speedup vs baseline: 1.8310x; 1.0356x over previous
//
#include <hip/hip_runtime.h>
#include <stdint.h>

#define T_   512
#define H_   256
#define OUTD 128

typedef unsigned long long u64;
typedef __attribute__((ext_vector_type(8))) short s8v;
typedef __attribute__((ext_vector_type(4))) float f4v;
typedef __attribute__((ext_vector_type(4))) unsigned u4v;

__device__ __forceinline__ f4v mfma16x16x32(s8v a, s8v b, f4v c) {
  return __builtin_amdgcn_mfma_f32_16x16x32_bf16(a, b, c, 0, 0, 0);
}

// fp32 -> bf16 hi (truncate) + bf16 lo (RN of remainder)
__device__ __forceinline__ void split_bf16(float f, short &hi, short &lo) {
  unsigned u  = __float_as_uint(f);
  unsigned uh = u & 0xffff0000u;
  hi = (short)(uh >> 16);
  float r = f - __uint_as_float(uh);
  unsigned ur = __float_as_uint(r);
  lo = (short)((ur + 0x7fffu + ((ur >> 16) & 1u)) >> 16);
}

__device__ __forceinline__ unsigned pack_hilo(float f) {
  short hi, lo; split_bf16(f, hi, lo);
  return ((unsigned)(unsigned short)hi << 16) | (unsigned)(unsigned short)lo;
}

// 8 packed dwords (hi16|lo16) -> s8v of 8 hi-bf16 and s8v of 8 lo-bf16
__device__ __forceinline__ void unpk(u4v A, u4v B, s8v &hi, s8v &lo) {
  union U { unsigned u[4]; s8v v; };
  U H, L;
  H.u[0] = __builtin_amdgcn_perm(A.y, A.x, 0x07060302u);
  H.u[1] = __builtin_amdgcn_perm(A.w, A.z, 0x07060302u);
  H.u[2] = __builtin_amdgcn_perm(B.y, B.x, 0x07060302u);
  H.u[3] = __builtin_amdgcn_perm(B.w, B.z, 0x07060302u);
  L.u[0] = __builtin_amdgcn_perm(A.y, A.x, 0x05040100u);
  L.u[1] = __builtin_amdgcn_perm(A.w, A.z, 0x05040100u);
  L.u[2] = __builtin_amdgcn_perm(B.y, B.x, 0x05040100u);
  L.u[3] = __builtin_amdgcn_perm(B.w, B.z, 0x05040100u);
  hi = H.v; lo = L.v;
}

__device__ __forceinline__ float sig_(float x) { return 1.f / (1.f + __expf(-x)); }
__device__ __forceinline__ float th_(float x)  { float e = __expf(2.f * x); return 1.f - 2.f / (e + 1.f); }

struct SMem {
  unsigned xpk[16][268];
  unsigned hpk[16][268];
  float gl[4][16][33];
  float bias[128];
};  // ~43.3 KB (1 block/CU)

// Partition: 32 units/member, 8 members/group, 16 groups/layer, 256 blocks
// total = 1 block/CU. Weights register-resident.
//
// XCD CO-LOCATION (round 6, the one change vs round 5): with round-robin
// dispatch XCD = bid&7, the old mapping (g=bid>>3) scattered each group's 8
// members across all 8 XCDs — every exchange transaction was cross-XCD
// (~700-900cy through fabric/L3). New mapping puts L0 groups {2x,2x+1} AND
// L1 groups {2x,2x+1} on XCD x: the whole all-to-all h exchange and the
// L0->L1 x handoff become XCD-local L2 traffic (~200-300cy). Pure bijection;
// exchange buffers are keyed by (g,mem), so protocol/correctness unchanged.
// If the dispatch mapping assumption is wrong this is merely perf-neutral.
//
// Exchange protocol: entry = u64 (tag<<32 | bf16hi<<16 | bf16lo), tag = step+1.
// bx0 (layer0 h / layer1 x) depth-4 (slot = s&3); bx1 (layer1 own) depth-2.
// Tag-equality spin on exactly the data each thread consumes (8B atomicity =>
// tag/data consistent). Own-group recurrence self-synchronizing at depth>=2.
// L0 publishing step s overwrites x(s-4) => needs rflag >= s-3; rflag is
// PREFETCHED at step top, evaluated before publish (RT hidden under step).
// L1's x(s) prefetched before the h-spin, verified after (RT hidden under h RT).
template <int LAYER>
__device__ __forceinline__ void lstm_body(
    SMem* sm,
    const float* __restrict__ xin,
    const float* __restrict__ Wih, const float* __restrict__ Whh,
    const float* __restrict__ bih, const float* __restrict__ bhh,
    u64* bx_x,        // LAYER==1: consumed exchange (layer0 h, depth 4)
    u64* bx_own,      // produced exchange (L0: bx0 depth 4; L1: bx1 depth 2)
    unsigned* rflag,  // [16 groups][8 members], stride 16 dwords
    float* h1l,       // LAYER==1: last h out [256,256]
    int g, int mem)
{
  constexpr int KX  = (LAYER == 0) ? 128 : 256;
  constexpr int NKX = KX / 32;
  constexpr int OD  = (LAYER == 0) ? 4 : 2;   // own exchange depth
  const int tid = threadIdx.x;
  const int w = tid >> 6, lane = tid & 63, n = lane & 15, q = lane >> 4;
  const int bb = tid >> 4, uu = tid & 15;
  const int B0 = g * 16, U0 = mem * 32;

  // ---- weight slice -> register B-fragments (bf16 hi/lo), once ----
  // wave w = gate w; 2 N-tiles of 16 units each (t=0,1)
  s8v wxh[2][NKX], wxl[2][NKX], whhh[2][8], whhl[2][8];
  #pragma unroll
  for (int t = 0; t < 2; ++t) {
    const int row = w * 256 + U0 + t * 16 + n;
    #pragma unroll
    for (int kf = 0; kf < NKX; ++kf) {
      s8v vh, vl;
      #pragma unroll
      for (int j = 0; j < 8; ++j) { short hi, lo; split_bf16(Wih[row * KX + kf * 32 + q * 8 + j], hi, lo); vh[j] = hi; vl[j] = lo; }
      wxh[t][kf] = vh; wxl[t][kf] = vl;
    }
    #pragma unroll
    for (int kf = 0; kf < 8; ++kf) {
      s8v vh, vl;
      #pragma unroll
      for (int j = 0; j < 8; ++j) { short hi, lo; split_bf16(Whh[row * 256 + kf * 32 + q * 8 + j], hi, lo); vh[j] = hi; vl[j] = lo; }
      whhh[t][kf] = vh; whhl[t][kf] = vl;
    }
  }
  if (tid < 128) {
    int gate = tid >> 5, u = tid & 31;
    int grow = gate * 256 + U0 + u;
    sm->bias[tid] = bih[grow] + bhh[grow];
  }

  u64* own = bx_own + (size_t)g * OD * 4096;
  u64* src = (LAYER == 1) ? (bx_x + (size_t)g * 4 * 4096) : nullptr;
  unsigned* rfg    = rflag + g * 128;       // member m's flag at rfg[m*16]
  unsigned* rfself = rfg + mem * 16;

  float c0 = 0.f, c1 = 0.f;

  for (int s = 0; s < T_; ++s) {
    // ---- layer0: fp32 x prefetch (issued early, overlaps spins) ----
    float xv[8];
    if (LAYER == 0) {
      const float* px = xin + ((size_t)(B0 + bb) * T_ + s) * 128 + uu * 8;
      float4 v0 = *(const float4*)px, v1 = *(const float4*)(px + 4);
      xv[0] = v0.x; xv[1] = v0.y; xv[2] = v0.z; xv[3] = v0.w;
      xv[4] = v1.x; xv[5] = v1.y; xv[6] = v1.z; xv[7] = v1.w;
    }

    // ---- layer0: rflag PREFETCH (evaluated just before publish) ----
    unsigned rfv = 0xffffffffu;
    if (LAYER == 0 && s >= 4 && w == 0 && lane < 8)
      rfv = __hip_atomic_load(&rfg[lane * 16], __ATOMIC_RELAXED, __HIP_MEMORY_SCOPE_AGENT);

    // ---- layer1: x PREFETCH (L0 runs ahead; verify after the h spin) ----
    u64 xp[16];
    if (LAYER == 1) {
      const u64* pbx = src + (size_t)(s & 3) * 4096;
      #pragma unroll
      for (int i = 0; i < 16; ++i)
        xp[i] = __hip_atomic_load(&pbx[i * 256 + tid], __ATOMIC_RELAXED, __HIP_MEMORY_SCOPE_AGENT);
    }

    // ---- spin-consume own group's h_{s-1} (the fundamental RT) ----
    if (s > 0) {
      const u64* pbh = own + (size_t)((s - 1) & (OD - 1)) * 4096;
      const unsigned htag = (unsigned)s;
      u64 hv64[16]; int it = 0;
      for (;;) {
        bool ok = true;
        #pragma unroll
        for (int i = 0; i < 16; ++i)
          hv64[i] = __hip_atomic_load(&pbh[i * 256 + tid], __ATOMIC_RELAXED, __HIP_MEMORY_SCOPE_AGENT);
        #pragma unroll
        for (int i = 0; i < 16; ++i) ok &= ((unsigned)(hv64[i] >> 32) == htag);
        if (ok) break;
        if (++it >= 50000) break;          // no-hang safety
        __builtin_amdgcn_s_sleep(1);
      }
      #pragma unroll
      for (int i = 0; i < 16; ++i)
        sm->hpk[i][tid] = (unsigned)hv64[i];
    } else {
      #pragma unroll
      for (int i = 0; i < 16; ++i) sm->hpk[i][tid] = 0u;
    }

    // ---- layer1: verify prefetched x tags; rare-miss fallback spin ----
    if (LAYER == 1) {
      const u64* pbx = src + (size_t)(s & 3) * 4096;
      const unsigned xtag = (unsigned)(s + 1);
      bool ok = true;
      #pragma unroll
      for (int i = 0; i < 16; ++i) ok &= ((unsigned)(xp[i] >> 32) == xtag);
      if (!ok) {
        int it = 0;
        for (;;) {
          ok = true;
          #pragma unroll
          for (int i = 0; i < 16; ++i)
            xp[i] = __hip_atomic_load(&pbx[i * 256 + tid], __ATOMIC_RELAXED, __HIP_MEMORY_SCOPE_AGENT);
          #pragma unroll
          for (int i = 0; i < 16; ++i) ok &= ((unsigned)(xp[i] >> 32) == xtag);
          if (ok) break;
          if (++it >= 50000) break;        // no-hang safety
          __builtin_amdgcn_s_sleep(1);
        }
      }
      #pragma unroll
      for (int i = 0; i < 16; ++i)
        sm->xpk[i][tid] = (unsigned)xp[i];
    }

    // ---- layer0: stage fp32 x as packed bf16 hi|lo ----
    if (LAYER == 0) {
      unsigned dp[8];
      #pragma unroll
      for (int j = 0; j < 8; ++j) dp[j] = pack_hilo(xv[j]);
      u4v w0 = {dp[0], dp[1], dp[2], dp[3]};
      u4v w1 = {dp[4], dp[5], dp[6], dp[7]};
      *(u4v*)&sm->xpk[bb][uu * 8]     = w0;
      *(u4v*)&sm->xpk[bb][uu * 8 + 4] = w1;
    }
    __syncthreads();

    // layer1: publish read-progress (all threads' loads completed at barrier)
    if (LAYER == 1 && tid == 0)
      __hip_atomic_store(rfself, (unsigned)(s + 1), __ATOMIC_RELAXED, __HIP_MEMORY_SCOPE_AGENT);

    // ---- bf16x3 MFMA, 2 N-tiles per wave: hi*hi + lo*hi + hi*lo ----
    f4v a00 = {0.f,0.f,0.f,0.f}, a01 = a00, a02 = a00;
    f4v a10 = a00, a11 = a00, a12 = a00;
    #pragma unroll
    for (int kf = 0; kf < NKX; ++kf) {
      u4v A0 = *(const u4v*)&sm->xpk[n][kf * 32 + q * 8];
      u4v A1 = *(const u4v*)&sm->xpk[n][kf * 32 + q * 8 + 4];
      s8v ah, al; unpk(A0, A1, ah, al);
      a00 = mfma16x16x32(ah, wxh[0][kf], a00);
      a01 = mfma16x16x32(al, wxh[0][kf], a01);
      a02 = mfma16x16x32(ah, wxl[0][kf], a02);
      a10 = mfma16x16x32(ah, wxh[1][kf], a10);
      a11 = mfma16x16x32(al, wxh[1][kf], a11);
      a12 = mfma16x16x32(ah, wxl[1][kf], a12);
    }
    #pragma unroll
    for (int kf = 0; kf < 8; ++kf) {
      u4v A0 = *(const u4v*)&sm->hpk[n][kf * 32 + q * 8];
      u4v A1 = *(const u4v*)&sm->hpk[n][kf * 32 + q * 8 + 4];
      s8v ah, al; unpk(A0, A1, ah, al);
      a00 = mfma16x16x32(ah, whhh[0][kf], a00);
      a01 = mfma16x16x32(al, whhh[0][kf], a01);
      a02 = mfma16x16x32(ah, whhl[0][kf], a02);
      a10 = mfma16x16x32(ah, whhh[1][kf], a10);
      a11 = mfma16x16x32(al, whhh[1][kf], a11);
      a12 = mfma16x16x32(ah, whhl[1][kf], a12);
    }
    f4v D0 = a00 + (a01 + a02);
    f4v D1 = a10 + (a11 + a12);
    #pragma unroll
    for (int r = 0; r < 4; ++r) {
      sm->gl[w][q * 4 + r][n]      = D0[r];
      sm->gl[w][q * 4 + r][16 + n] = D1[r];
    }
    __syncthreads();

    // ---- activations + state (2 units per thread: uu and uu+16) ----
    float h0v, h1v;
    {
      float pi = sm->gl[0][bb][uu] + sm->bias[uu];
      float pf = sm->gl[1][bb][uu] + sm->bias[32 + uu];
      float pg = sm->gl[2][bb][uu] + sm->bias[64 + uu];
      float po = sm->gl[3][bb][uu] + sm->bias[96 + uu];
      float ig = sig_(pi), fg = sig_(pf), gg = th_(pg), og = sig_(po);
      c0 = fg * c0 + ig * gg;
      h0v = og * th_(c0);
    }
    {
      int u = uu + 16;
      float pi = sm->gl[0][bb][u] + sm->bias[u];
      float pf = sm->gl[1][bb][u] + sm->bias[32 + u];
      float pg = sm->gl[2][bb][u] + sm->bias[64 + u];
      float po = sm->gl[3][bb][u] + sm->bias[96 + u];
      float ig = sig_(pi), fg = sig_(pf), gg = th_(pg), og = sig_(po);
      c1 = fg * c1 + ig * gg;
      h1v = og * th_(c1);
    }

    // ---- layer0: evaluate prefetched back-pressure (RT already hidden).
    //      Publishing step s overwrites x(s-4): need rflag >= s-3. ----
    if (LAYER == 0) {
      if (s >= 4 && w == 0) {
        const unsigned tgt = (unsigned)(s - 3);
        bool ok = (lane < 8) ? (rfv >= tgt) : true;
        if (!__all((int)ok)) {
          int it = 0;
          for (;;) {
            unsigned v = (lane < 8)
              ? __hip_atomic_load(&rfg[lane * 16], __ATOMIC_RELAXED, __HIP_MEMORY_SCOPE_AGENT)
              : tgt;
            if (__all((int)(v >= tgt))) break;
            if (++it >= 50000) break;
            __builtin_amdgcn_s_sleep(1);
          }
        }
      }
      __syncthreads();
    }

    // ---- publish h (tagged, fire-and-forget; 2 entries/thread) ----
    const u64 tagw = (u64)(unsigned)(s + 1) << 32;
    u64* slot = own + (size_t)(s & (OD - 1)) * 4096 + bb * 256 + U0 + uu;
    __hip_atomic_store(slot,      tagw | (u64)pack_hilo(h0v), __ATOMIC_RELAXED, __HIP_MEMORY_SCOPE_AGENT);
    __hip_atomic_store(slot + 16, tagw | (u64)pack_hilo(h1v), __ATOMIC_RELAXED, __HIP_MEMORY_SCOPE_AGENT);

    if (LAYER == 1 && s == T_ - 1) {
      h1l[(B0 + bb) * H_ + U0 + uu]      = h0v;
      h1l[(B0 + bb) * H_ + U0 + 16 + uu] = h1v;
    }
  }
}

__global__ __launch_bounds__(256, 1) void lstm_fused(
    const float* __restrict__ x,
    const float* __restrict__ Wih0, const float* __restrict__ Whh0,
    const float* __restrict__ bih0, const float* __restrict__ bhh0,
    const float* __restrict__ Wih1, const float* __restrict__ Whh1,
    const float* __restrict__ bih1, const float* __restrict__ bhh1,
    u64* bx0, u64* bx1, unsigned* rflag, float* h1l)
{
  __shared__ SMem sm;
  // XCD co-location map (assumes round-robin dispatch XCD = bid & 7):
  // XCD x hosts: slots 0-7  = L0 group 2x,   members 0-7
  //              slots 8-15 = L0 group 2x+1, members 0-7
  //              slots 16-23= L1 group 2x,   members 0-7
  //              slots 24-31= L1 group 2x+1, members 0-7
  const int bid   = blockIdx.x;
  const int xcd   = bid & 7;
  const int slot  = bid >> 3;            // 0..31
  const int layer = slot >> 4;           // 0 or 1
  const int g     = 2 * xcd + ((slot >> 3) & 1);
  const int mem   = slot & 7;
  if (layer == 0) {
    lstm_body<0>(&sm, x, Wih0, Whh0, bih0, bhh0, nullptr, bx0, rflag, nullptr,
                 g, mem);
  } else {
    lstm_body<1>(&sm, nullptr, Wih1, Whh1, bih1, bhh1, bx0, bx1, rflag, h1l,
                 g, mem);
  }
}

__global__ void fc_kernel(const float* __restrict__ h1l, const float* __restrict__ Wfc,
                          float* __restrict__ out) {
  __shared__ float hs[H_];
  const int b = blockIdx.x, o = threadIdx.x;
  hs[o]       = h1l[b * H_ + o];
  hs[o + 128] = h1l[b * H_ + o + 128];
  __syncthreads();
  float acc = 0.f;
  #pragma unroll 8
  for (int u = 0; u < H_; u += 4) {
    float4 wv = *(const float4*)&Wfc[o * H_ + u];
    acc += wv.x * hs[u] + wv.y * hs[u + 1] + wv.z * hs[u + 2] + wv.w * hs[u + 3];
  }
  out[b * OUTD + o] = acc;
}

extern "C" void kernel_launch(void* const* d_in, const int* in_sizes, int n_in,
                              void* d_out, int out_size, void* d_ws, size_t ws_size,
                              hipStream_t stream) {
  const float* x    = (const float*)d_in[0];
  const float* Wih0 = (const float*)d_in[1];
  const float* Whh0 = (const float*)d_in[2];
  const float* bih0 = (const float*)d_in[3];
  const float* bhh0 = (const float*)d_in[4];
  const float* Wih1 = (const float*)d_in[5];
  const float* Whh1 = (const float*)d_in[6];
  const float* bih1 = (const float*)d_in[7];
  const float* bhh1 = (const float*)d_in[8];
  const float* Wfc  = (const float*)d_in[9];

  // ws layout: bx0 (2 MiB, depth 4) | bx1 (1 MiB, depth 2) | rflag (16 KiB) |
  //            h1l (256 KiB)
  u64*      bx0   = (u64*)d_ws;                 // 16*4*4096
  u64*      bx1   = bx0 + 262144;               // 16*2*4096
  unsigned* rflag = (unsigned*)(bx1 + 131072);  // 16*8*16 used
  float*    h1l   = (float*)(rflag + 4096);     // 256*256

  // rflag must start at 0 (poison 0xAA.. would spoof the >= back-pressure check;
  // exchange tags use equality so poison can never match them).
  hipMemsetAsync(rflag, 0, 4096 * sizeof(unsigned), stream);

  lstm_fused<<<256, 256, 0, stream>>>(x, Wih0, Whh0, bih0, bhh0,
                                      Wih1, Whh1, bih1, bhh1,
                                      bx0, bx1, rflag, h1l);
  fc_kernel<<<256, 128, 0, stream>>>(h1l, Wfc, (float*)d_out);
}

// Round 10
// 2342.909 us; speedup vs baseline: 1.8353x; 1.0024x over previous
//
#include <hip/hip_runtime.h>
#include <stdint.h>

#define T_   512
#define H_   256
#define OUTD 128

typedef unsigned long long u64;
typedef __attribute__((ext_vector_type(8))) short s8v;
typedef __attribute__((ext_vector_type(4))) float f4v;
typedef __attribute__((ext_vector_type(4))) unsigned u4v;

__device__ __forceinline__ f4v mfma16x16x32(s8v a, s8v b, f4v c) {
  return __builtin_amdgcn_mfma_f32_16x16x32_bf16(a, b, c, 0, 0, 0);
}

// fp32 -> bf16 hi (truncate) + bf16 lo (RN of remainder)
__device__ __forceinline__ void split_bf16(float f, short &hi, short &lo) {
  unsigned u  = __float_as_uint(f);
  unsigned uh = u & 0xffff0000u;
  hi = (short)(uh >> 16);
  float r = f - __uint_as_float(uh);
  unsigned ur = __float_as_uint(r);
  lo = (short)((ur + 0x7fffu + ((ur >> 16) & 1u)) >> 16);
}

__device__ __forceinline__ unsigned pack_hilo(float f) {
  short hi, lo; split_bf16(f, hi, lo);
  return ((unsigned)(unsigned short)hi << 16) | (unsigned)(unsigned short)lo;
}

// 8 packed dwords (hi16|lo16) -> s8v of 8 hi-bf16 and s8v of 8 lo-bf16
__device__ __forceinline__ void unpk(u4v A, u4v B, s8v &hi, s8v &lo) {
  union U { unsigned u[4]; s8v v; };
  U H, L;
  H.u[0] = __builtin_amdgcn_perm(A.y, A.x, 0x07060302u);
  H.u[1] = __builtin_amdgcn_perm(A.w, A.z, 0x07060302u);
  H.u[2] = __builtin_amdgcn_perm(B.y, B.x, 0x07060302u);
  H.u[3] = __builtin_amdgcn_perm(B.w, B.z, 0x07060302u);
  L.u[0] = __builtin_amdgcn_perm(A.y, A.x, 0x05040100u);
  L.u[1] = __builtin_amdgcn_perm(A.w, A.z, 0x05040100u);
  L.u[2] = __builtin_amdgcn_perm(B.y, B.x, 0x05040100u);
  L.u[3] = __builtin_amdgcn_perm(B.w, B.z, 0x05040100u);
  hi = H.v; lo = L.v;
}

__device__ __forceinline__ float sig_(float x) { return 1.f / (1.f + __expf(-x)); }
__device__ __forceinline__ float th_(float x)  { float e = __expf(2.f * x); return 1.f - 2.f / (e + 1.f); }

struct SMem {
  unsigned xpk[16][268];
  unsigned hpk[16][268];
  float gl[4][16][33];
  float bias[128];
};  // ~43.3 KB (1 block/CU)

// === ROUND 10: byte-identical revert to round 6 (best passing, 2348 us). ===
// History of the exchange-scope axis, for the record:
//   r8: L2-scope (wg-scope store + sc0 load) with static bid&7 XCD map ->
//       absmax fail (sparse stale pairs).
//   r9: same L2-scope with RUNTIME XCC_ID claiming (mapping provably
//       same-XCD) -> IDENTICAL failure signature. Conclusion: the wg-store +
//       sc0-load pair does not provide reliable same-XCD cross-CU visibility
//       on this part; L2-scope exchange is unsound here. Agent scope (MALL
//       coherence point) is required for correctness -> its ~MALL RT is the
//       structural latency floor of this decomposition.
//
// Partition: 32 units/member, 8 members/group, 16 groups/layer, 256 blocks
// total = 1 block/CU. XCD co-location (round 6): group members + cross-layer
// partner groups share an XCD under round-robin dispatch (FETCH_SIZE
// 2.39GB -> 320MB confirmed ~90%+ locality; with agent scope a residual
// cross-XCD pair is only slower, never incorrect). Weights register-resident
// (unified VGPR+AGPR file: 244 arch VGPR + AGPR weight fragments).
//
// Exchange protocol: entry = u64 (tag<<32 | bf16hi<<16 | bf16lo), tag = step+1.
// bx0 (layer0 h / layer1 x) depth-4 (slot = s&3); bx1 (layer1 own) depth-2.
// Tag-equality spin on exactly the data each thread consumes (8B single-store
// atomicity => tag/data consistent). Own-group recurrence self-synchronizing
// at depth>=2. L0 publishing step s overwrites x(s-4) => needs rflag >= s-3;
// rflag PREFETCHED at step top, evaluated before publish (RT hidden under
// step). L1's x(s) prefetched before the h-spin, verified after (RT hidden
// under h RT).
template <int LAYER>
__device__ __forceinline__ void lstm_body(
    SMem* sm,
    const float* __restrict__ xin,
    const float* __restrict__ Wih, const float* __restrict__ Whh,
    const float* __restrict__ bih, const float* __restrict__ bhh,
    u64* bx_x,        // LAYER==1: consumed exchange (layer0 h, depth 4)
    u64* bx_own,      // produced exchange (L0: bx0 depth 4; L1: bx1 depth 2)
    unsigned* rflag,  // [16 groups][8 members], stride 16 dwords
    float* h1l,       // LAYER==1: last h out [256,256]
    int g, int mem)
{
  constexpr int KX  = (LAYER == 0) ? 128 : 256;
  constexpr int NKX = KX / 32;
  constexpr int OD  = (LAYER == 0) ? 4 : 2;   // own exchange depth
  const int tid = threadIdx.x;
  const int w = tid >> 6, lane = tid & 63, n = lane & 15, q = lane >> 4;
  const int bb = tid >> 4, uu = tid & 15;
  const int B0 = g * 16, U0 = mem * 32;

  // ---- weight slice -> register B-fragments (bf16 hi/lo), once ----
  // wave w = gate w; 2 N-tiles of 16 units each (t=0,1)
  s8v wxh[2][NKX], wxl[2][NKX], whhh[2][8], whhl[2][8];
  #pragma unroll
  for (int t = 0; t < 2; ++t) {
    const int row = w * 256 + U0 + t * 16 + n;
    #pragma unroll
    for (int kf = 0; kf < NKX; ++kf) {
      s8v vh, vl;
      #pragma unroll
      for (int j = 0; j < 8; ++j) { short hi, lo; split_bf16(Wih[row * KX + kf * 32 + q * 8 + j], hi, lo); vh[j] = hi; vl[j] = lo; }
      wxh[t][kf] = vh; wxl[t][kf] = vl;
    }
    #pragma unroll
    for (int kf = 0; kf < 8; ++kf) {
      s8v vh, vl;
      #pragma unroll
      for (int j = 0; j < 8; ++j) { short hi, lo; split_bf16(Whh[row * 256 + kf * 32 + q * 8 + j], hi, lo); vh[j] = hi; vl[j] = lo; }
      whhh[t][kf] = vh; whhl[t][kf] = vl;
    }
  }
  if (tid < 128) {
    int gate = tid >> 5, u = tid & 31;
    int grow = gate * 256 + U0 + u;
    sm->bias[tid] = bih[grow] + bhh[grow];
  }

  u64* own = bx_own + (size_t)g * OD * 4096;
  u64* src = (LAYER == 1) ? (bx_x + (size_t)g * 4 * 4096) : nullptr;
  unsigned* rfg    = rflag + g * 128;       // member m's flag at rfg[m*16]
  unsigned* rfself = rfg + mem * 16;

  float c0 = 0.f, c1 = 0.f;

  for (int s = 0; s < T_; ++s) {
    // ---- layer0: fp32 x prefetch (issued early, overlaps spins) ----
    float xv[8];
    if (LAYER == 0) {
      const float* px = xin + ((size_t)(B0 + bb) * T_ + s) * 128 + uu * 8;
      float4 v0 = *(const float4*)px, v1 = *(const float4*)(px + 4);
      xv[0] = v0.x; xv[1] = v0.y; xv[2] = v0.z; xv[3] = v0.w;
      xv[4] = v1.x; xv[5] = v1.y; xv[6] = v1.z; xv[7] = v1.w;
    }

    // ---- layer0: rflag PREFETCH (evaluated just before publish) ----
    unsigned rfv = 0xffffffffu;
    if (LAYER == 0 && s >= 4 && w == 0 && lane < 8)
      rfv = __hip_atomic_load(&rfg[lane * 16], __ATOMIC_RELAXED, __HIP_MEMORY_SCOPE_AGENT);

    // ---- layer1: x PREFETCH (L0 runs ahead; verify after the h spin) ----
    u64 xp[16];
    if (LAYER == 1) {
      const u64* pbx = src + (size_t)(s & 3) * 4096;
      #pragma unroll
      for (int i = 0; i < 16; ++i)
        xp[i] = __hip_atomic_load(&pbx[i * 256 + tid], __ATOMIC_RELAXED, __HIP_MEMORY_SCOPE_AGENT);
    }

    // ---- spin-consume own group's h_{s-1} (the fundamental RT) ----
    if (s > 0) {
      const u64* pbh = own + (size_t)((s - 1) & (OD - 1)) * 4096;
      const unsigned htag = (unsigned)s;
      u64 hv64[16]; int it = 0;
      for (;;) {
        bool ok = true;
        #pragma unroll
        for (int i = 0; i < 16; ++i)
          hv64[i] = __hip_atomic_load(&pbh[i * 256 + tid], __ATOMIC_RELAXED, __HIP_MEMORY_SCOPE_AGENT);
        #pragma unroll
        for (int i = 0; i < 16; ++i) ok &= ((unsigned)(hv64[i] >> 32) == htag);
        if (ok) break;
        if (++it >= 50000) break;          // no-hang safety
        __builtin_amdgcn_s_sleep(1);
      }
      #pragma unroll
      for (int i = 0; i < 16; ++i)
        sm->hpk[i][tid] = (unsigned)hv64[i];
    } else {
      #pragma unroll
      for (int i = 0; i < 16; ++i) sm->hpk[i][tid] = 0u;
    }

    // ---- layer1: verify prefetched x tags; rare-miss fallback spin ----
    if (LAYER == 1) {
      const u64* pbx = src + (size_t)(s & 3) * 4096;
      const unsigned xtag = (unsigned)(s + 1);
      bool ok = true;
      #pragma unroll
      for (int i = 0; i < 16; ++i) ok &= ((unsigned)(xp[i] >> 32) == xtag);
      if (!ok) {
        int it = 0;
        for (;;) {
          ok = true;
          #pragma unroll
          for (int i = 0; i < 16; ++i)
            xp[i] = __hip_atomic_load(&pbx[i * 256 + tid], __ATOMIC_RELAXED, __HIP_MEMORY_SCOPE_AGENT);
          #pragma unroll
          for (int i = 0; i < 16; ++i) ok &= ((unsigned)(xp[i] >> 32) == xtag);
          if (ok) break;
          if (++it >= 50000) break;        // no-hang safety
          __builtin_amdgcn_s_sleep(1);
        }
      }
      #pragma unroll
      for (int i = 0; i < 16; ++i)
        sm->xpk[i][tid] = (unsigned)xp[i];
    }

    // ---- layer0: stage fp32 x as packed bf16 hi|lo ----
    if (LAYER == 0) {
      unsigned dp[8];
      #pragma unroll
      for (int j = 0; j < 8; ++j) dp[j] = pack_hilo(xv[j]);
      u4v w0 = {dp[0], dp[1], dp[2], dp[3]};
      u4v w1 = {dp[4], dp[5], dp[6], dp[7]};
      *(u4v*)&sm->xpk[bb][uu * 8]     = w0;
      *(u4v*)&sm->xpk[bb][uu * 8 + 4] = w1;
    }
    __syncthreads();

    // layer1: publish read-progress (all threads' loads completed at barrier)
    if (LAYER == 1 && tid == 0)
      __hip_atomic_store(rfself, (unsigned)(s + 1), __ATOMIC_RELAXED, __HIP_MEMORY_SCOPE_AGENT);

    // ---- bf16x3 MFMA, 2 N-tiles per wave: hi*hi + lo*hi + hi*lo ----
    f4v a00 = {0.f,0.f,0.f,0.f}, a01 = a00, a02 = a00;
    f4v a10 = a00, a11 = a00, a12 = a00;
    #pragma unroll
    for (int kf = 0; kf < NKX; ++kf) {
      u4v A0 = *(const u4v*)&sm->xpk[n][kf * 32 + q * 8];
      u4v A1 = *(const u4v*)&sm->xpk[n][kf * 32 + q * 8 + 4];
      s8v ah, al; unpk(A0, A1, ah, al);
      a00 = mfma16x16x32(ah, wxh[0][kf], a00);
      a01 = mfma16x16x32(al, wxh[0][kf], a01);
      a02 = mfma16x16x32(ah, wxl[0][kf], a02);
      a10 = mfma16x16x32(ah, wxh[1][kf], a10);
      a11 = mfma16x16x32(al, wxh[1][kf], a11);
      a12 = mfma16x16x32(ah, wxl[1][kf], a12);
    }
    #pragma unroll
    for (int kf = 0; kf < 8; ++kf) {
      u4v A0 = *(const u4v*)&sm->hpk[n][kf * 32 + q * 8];
      u4v A1 = *(const u4v*)&sm->hpk[n][kf * 32 + q * 8 + 4];
      s8v ah, al; unpk(A0, A1, ah, al);
      a00 = mfma16x16x32(ah, whhh[0][kf], a00);
      a01 = mfma16x16x32(al, whhh[0][kf], a01);
      a02 = mfma16x16x32(ah, whhl[0][kf], a02);
      a10 = mfma16x16x32(ah, whhh[1][kf], a10);
      a11 = mfma16x16x32(al, whhh[1][kf], a11);
      a12 = mfma16x16x32(ah, whhl[1][kf], a12);
    }
    f4v D0 = a00 + (a01 + a02);
    f4v D1 = a10 + (a11 + a12);
    #pragma unroll
    for (int r = 0; r < 4; ++r) {
      sm->gl[w][q * 4 + r][n]      = D0[r];
      sm->gl[w][q * 4 + r][16 + n] = D1[r];
    }
    __syncthreads();

    // ---- activations + state (2 units per thread: uu and uu+16) ----
    float h0v, h1v;
    {
      float pi = sm->gl[0][bb][uu] + sm->bias[uu];
      float pf = sm->gl[1][bb][uu] + sm->bias[32 + uu];
      float pg = sm->gl[2][bb][uu] + sm->bias[64 + uu];
      float po = sm->gl[3][bb][uu] + sm->bias[96 + uu];
      float ig = sig_(pi), fg = sig_(pf), gg = th_(pg), og = sig_(po);
      c0 = fg * c0 + ig * gg;
      h0v = og * th_(c0);
    }
    {
      int u = uu + 16;
      float pi = sm->gl[0][bb][u] + sm->bias[u];
      float pf = sm->gl[1][bb][u] + sm->bias[32 + u];
      float pg = sm->gl[2][bb][u] + sm->bias[64 + u];
      float po = sm->gl[3][bb][u] + sm->bias[96 + u];
      float ig = sig_(pi), fg = sig_(pf), gg = th_(pg), og = sig_(po);
      c1 = fg * c1 + ig * gg;
      h1v = og * th_(c1);
    }

    // ---- layer0: evaluate prefetched back-pressure (RT already hidden).
    //      Publishing step s overwrites x(s-4): need rflag >= s-3. ----
    if (LAYER == 0) {
      if (s >= 4 && w == 0) {
        const unsigned tgt = (unsigned)(s - 3);
        bool ok = (lane < 8) ? (rfv >= tgt) : true;
        if (!__all((int)ok)) {
          int it = 0;
          for (;;) {
            unsigned v = (lane < 8)
              ? __hip_atomic_load(&rfg[lane * 16], __ATOMIC_RELAXED, __HIP_MEMORY_SCOPE_AGENT)
              : tgt;
            if (__all((int)(v >= tgt))) break;
            if (++it >= 50000) break;
            __builtin_amdgcn_s_sleep(1);
          }
        }
      }
      __syncthreads();
    }

    // ---- publish h (tagged, fire-and-forget; 2 entries/thread) ----
    const u64 tagw = (u64)(unsigned)(s + 1) << 32;
    u64* slot = own + (size_t)(s & (OD - 1)) * 4096 + bb * 256 + U0 + uu;
    __hip_atomic_store(slot,      tagw | (u64)pack_hilo(h0v), __ATOMIC_RELAXED, __HIP_MEMORY_SCOPE_AGENT);
    __hip_atomic_store(slot + 16, tagw | (u64)pack_hilo(h1v), __ATOMIC_RELAXED, __HIP_MEMORY_SCOPE_AGENT);

    if (LAYER == 1 && s == T_ - 1) {
      h1l[(B0 + bb) * H_ + U0 + uu]      = h0v;
      h1l[(B0 + bb) * H_ + U0 + 16 + uu] = h1v;
    }
  }
}

__global__ __launch_bounds__(256, 1) void lstm_fused(
    const float* __restrict__ x,
    const float* __restrict__ Wih0, const float* __restrict__ Whh0,
    const float* __restrict__ bih0, const float* __restrict__ bhh0,
    const float* __restrict__ Wih1, const float* __restrict__ Whh1,
    const float* __restrict__ bih1, const float* __restrict__ bhh1,
    u64* bx0, u64* bx1, unsigned* rflag, float* h1l)
{
  __shared__ SMem sm;
  // XCD co-location map (round-robin dispatch XCD = bid & 7):
  // XCD x hosts: slots 0-7  = L0 group 2x,   members 0-7
  //              slots 8-15 = L0 group 2x+1, members 0-7
  //              slots 16-23= L1 group 2x,   members 0-7
  //              slots 24-31= L1 group 2x+1, members 0-7
  // Perf heuristic only — with agent-scope exchange, a mismatched pair is
  // slower, never incorrect (G16-safe).
  const int bid   = blockIdx.x;
  const int xcd   = bid & 7;
  const int slot  = bid >> 3;            // 0..31
  const int layer = slot >> 4;           // 0 or 1
  const int g     = 2 * xcd + ((slot >> 3) & 1);
  const int mem   = slot & 7;
  if (layer == 0) {
    lstm_body<0>(&sm, x, Wih0, Whh0, bih0, bhh0, nullptr, bx0, rflag, nullptr,
                 g, mem);
  } else {
    lstm_body<1>(&sm, nullptr, Wih1, Whh1, bih1, bhh1, bx0, bx1, rflag, h1l,
                 g, mem);
  }
}

__global__ void fc_kernel(const float* __restrict__ h1l, const float* __restrict__ Wfc,
                          float* __restrict__ out) {
  __shared__ float hs[H_];
  const int b = blockIdx.x, o = threadIdx.x;
  hs[o]       = h1l[b * H_ + o];
  hs[o + 128] = h1l[b * H_ + o + 128];
  __syncthreads();
  float acc = 0.f;
  #pragma unroll 8
  for (int u = 0; u < H_; u += 4) {
    float4 wv = *(const float4*)&Wfc[o * H_ + u];
    acc += wv.x * hs[u] + wv.y * hs[u + 1] + wv.z * hs[u + 2] + wv.w * hs[u + 3];
  }
  out[b * OUTD + o] = acc;
}

extern "C" void kernel_launch(void* const* d_in, const int* in_sizes, int n_in,
                              void* d_out, int out_size, void* d_ws, size_t ws_size,
                              hipStream_t stream) {
  const float* x    = (const float*)d_in[0];
  const float* Wih0 = (const float*)d_in[1];
  const float* Whh0 = (const float*)d_in[2];
  const float* bih0 = (const float*)d_in[3];
  const float* bhh0 = (const float*)d_in[4];
  const float* Wih1 = (const float*)d_in[5];
  const float* Whh1 = (const float*)d_in[6];
  const float* bih1 = (const float*)d_in[7];
  const float* bhh1 = (const float*)d_in[8];
  const float* Wfc  = (const float*)d_in[9];

  // ws layout: bx0 (2 MiB, depth 4) | bx1 (1 MiB, depth 2) | rflag (16 KiB) |
  //            h1l (256 KiB)
  u64*      bx0   = (u64*)d_ws;                 // 16*4*4096
  u64*      bx1   = bx0 + 262144;               // 16*2*4096
  unsigned* rflag = (unsigned*)(bx1 + 131072);  // 16*8*16 used
  float*    h1l   = (float*)(rflag + 4096);     // 256*256

  // rflag must start at 0 (poison 0xAA.. would spoof the >= back-pressure check;
  // exchange tags use equality so poison can never match them).
  hipMemsetAsync(rflag, 0, 4096 * sizeof(unsigned), stream);

  lstm_fused<<<256, 256, 0, stream>>>(x, Wih0, Whh0, bih0, bhh0,
                                      Wih1, Whh1, bih1, bhh1,
                                      bx0, bx1, rflag, h1l);
  fc_kernel<<<256, 128, 0, stream>>>(h1l, Wfc, (float*)d_out);
}